// Round 1
// baseline (3549.970 us; speedup 1.0000x reference)
//
#include <hip/hip_runtime.h>
#include <math.h>

// ---------------------------------------------------------------------------
// SimpleTranslate encoder-decoder forward, MI355X/gfx950.
// Round 0: correctness-first. All matmuls via bf16 MFMA 16x16x32, fp32 accum.
// Residual stream / LN / softmax in fp32; GEMM inputs rounded to bf16 (RNE).
// Weights transposed+cast to bf16 [N][K] in workspace each call (harness
// re-poisons d_ws every timed launch).
// ---------------------------------------------------------------------------

typedef __bf16 bf16;
typedef bf16  bf16x8 __attribute__((ext_vector_type(8)));
typedef float f32x4  __attribute__((ext_vector_type(4)));

#define DEV __device__ __forceinline__

// Model constants (fixed by the problem)
// V=32000, SMAX=512, D=512, DH=64, H=8, M=2048, L=6, B=4, S=T=512

DEV f32x4 mfma16(bf16x8 a, bf16x8 b, f32x4 c) {
  return __builtin_amdgcn_mfma_f32_16x16x32_bf16(a, b, c, 0, 0, 0);
}

// ---------------------------------------------------------------------------
// Transpose + fp32->bf16 cast: in [Z][R][C] f32  ->  out [Z][C][R] bf16
// block (32,8), grid (C/32, R/32, Z). All R,C divisible by 32 here.
// ---------------------------------------------------------------------------
__global__ __launch_bounds__(256) void tcast_kernel(
    const float* __restrict__ in, bf16* __restrict__ out, const int R, const int C)
{
  __shared__ float tile[32][33];
  const long long zo = (long long)blockIdx.z * R * C;
  const int c0 = blockIdx.x * 32, r0 = blockIdx.y * 32;
  const int tx = threadIdx.x, ty = threadIdx.y;
#pragma unroll
  for (int i = 0; i < 32; i += 8)
    tile[ty + i][tx] = in[zo + (long long)(r0 + ty + i) * C + c0 + tx];
  __syncthreads();
#pragma unroll
  for (int i = 0; i < 32; i += 8)
    out[zo + (long long)(c0 + ty + i) * R + r0 + tx] = (bf16)tile[tx][ty + i];
}

// ---------------------------------------------------------------------------
// Embedding: x[row, :] = tok_emb[tok[row], :] + pos_emb[row % 512, :]  (fp32)
// grid = 2048 rows, block = 128 (x4 floats)
// ---------------------------------------------------------------------------
__global__ __launch_bounds__(128) void embed_kernel(
    const int* __restrict__ tok, const float* __restrict__ temb,
    const float* __restrict__ pemb, float* __restrict__ x)
{
  const int row  = blockIdx.x;
  const int sPos = row & 511;
  const int t    = tok[row];
  const int d    = threadIdx.x * 4;
  f32x4 a = *(const f32x4*)&temb[(long long)t * 512 + d];
  f32x4 p = *(const f32x4*)&pemb[(long long)sPos * 512 + d];
  *(f32x4*)&x[(long long)row * 512 + d] = a + p;
}

// ---------------------------------------------------------------------------
// LayerNorm row of 512, fp32 in, bf16 out. One wave per row (8 elems/lane).
// ---------------------------------------------------------------------------
__global__ __launch_bounds__(64) void ln_kernel(
    const float* __restrict__ x, const float* __restrict__ w,
    const float* __restrict__ b, bf16* __restrict__ out)
{
  const int row = blockIdx.x;
  const int lane = threadIdx.x;
  const float* xr = x + (long long)row * 512;
  f32x4 a0 = *(const f32x4*)&xr[lane * 8];
  f32x4 a1 = *(const f32x4*)&xr[lane * 8 + 4];
  float s = 0.f, q = 0.f;
#pragma unroll
  for (int k = 0; k < 4; ++k) { s += a0[k] + a1[k]; q += a0[k]*a0[k] + a1[k]*a1[k]; }
#pragma unroll
  for (int m = 1; m < 64; m <<= 1) { s += __shfl_xor(s, m); q += __shfl_xor(q, m); }
  const float mean = s * (1.f / 512.f);
  const float var  = q * (1.f / 512.f) - mean * mean;
  const float rs   = rsqrtf(var + 1e-5f);
  f32x4 w0 = *(const f32x4*)&w[lane * 8], w1 = *(const f32x4*)&w[lane * 8 + 4];
  f32x4 b0 = *(const f32x4*)&b[lane * 8], b1 = *(const f32x4*)&b[lane * 8 + 4];
  bf16x8 o;
#pragma unroll
  for (int k = 0; k < 4; ++k) {
    o[k]     = (bf16)((a0[k] - mean) * rs * w0[k] + b0[k]);
    o[k + 4] = (bf16)((a1[k] - mean) * rs * w1[k] + b1[k]);
  }
  *(bf16x8*)&out[(long long)row * 512 + lane * 8] = o;
}

// ---------------------------------------------------------------------------
// Masked softmax over rows of 512 fp32 scores -> bf16 probs.
// MODE 0: key mask (src token != 0, token index = column t)
// MODE 1: causal (t <= s)
// blockIdx.x = (b*8+h)*512 + s ; one wave per row.
// ---------------------------------------------------------------------------
template <int MODE>
__global__ __launch_bounds__(64) void softmax_kernel(
    const float* __restrict__ sc, bf16* __restrict__ pb,
    const int* __restrict__ srctok)
{
  const int row  = blockIdx.x;
  const int sPos = row & 511;
  const int b    = row >> 12;   // 4096 rows per batch (8 heads * 512)
  const int lane = threadIdx.x;
  const float* sr = sc + (long long)row * 512;
  f32x4 va = *(const f32x4*)&sr[lane * 8];
  f32x4 vb = *(const f32x4*)&sr[lane * 8 + 4];
  float v[8] = { va[0], va[1], va[2], va[3], vb[0], vb[1], vb[2], vb[3] };
  bool ok[8];
  if (MODE == 0) {
    const int* tk = srctok + b * 512 + lane * 8;
#pragma unroll
    for (int i = 0; i < 8; ++i) ok[i] = (tk[i] != 0);
  } else {
#pragma unroll
    for (int i = 0; i < 8; ++i) ok[i] = (lane * 8 + i) <= sPos;
  }
  float mx = -3.0e38f;
#pragma unroll
  for (int i = 0; i < 8; ++i) if (ok[i]) mx = fmaxf(mx, v[i]);
#pragma unroll
  for (int m = 1; m < 64; m <<= 1) mx = fmaxf(mx, __shfl_xor(mx, m));
  float e[8]; float sum = 0.f;
#pragma unroll
  for (int i = 0; i < 8; ++i) { e[i] = ok[i] ? __expf(v[i] - mx) : 0.f; sum += e[i]; }
#pragma unroll
  for (int m = 1; m < 64; m <<= 1) sum += __shfl_xor(sum, m);
  const float inv = 1.f / sum;
  bf16x8 o;
#pragma unroll
  for (int i = 0; i < 8; ++i) o[i] = (bf16)(e[i] * inv);
  *(bf16x8*)&pb[(long long)row * 512 + lane * 8] = o;
}

// ---------------------------------------------------------------------------
// Generic bf16 MFMA GEMM.  C[M,N] = A[M,K] * B^T  where B is given [N][K]
// (both bf16, row-major along K). 256 threads = 4 waves in a 2x2 grid; each
// wave computes (BM/2)x(BN/2) via 16x16x32 MFMA fragments. BK=64.
// LDS rows padded to 72 bf16 -> fragment ds_read_b128 is 2-way-bank (free).
// Batched via blockIdx.z with linear A/B strides; C offset =
// (z%HB)*sClo + (z/HB)*sChi (handles [B,S,H*64] style outputs).
// Epilogues:
//  0: C bf16 = v
//  1: C f32  = v*scale                       (attention scores)
//  2: C f32 += v + bias[col]                 (residual add, WO / FFN2)
//  3: C bf16 = gelu_exact(v + bias[col])     (FFN1)
//  4: C f32  = v + bias[col]                 (head logits)
//  5: q/k scatter: C bf16 [(b*8+h)*512+s][64] at [.., e]   (row=b*512+s, col=h*64+e)
//  6: v scatter:   C bf16 [(b*8+h)*64+e][512] at [.., s]   (transposed for PV)
// ---------------------------------------------------------------------------
template <int BM, int BN, int EPI>
__global__ __launch_bounds__(256) void gemm_kernel(
    const bf16* __restrict__ A, const bf16* __restrict__ Bw,
    void* __restrict__ Cc, const float* __restrict__ bias,
    const int K, const int lda, const int ldb, const int ldc,
    const long long sAz, const long long sBz,
    const long long sClo, const long long sChi, const int HB,
    const float scale)
{
  constexpr int BK = 64;
  constexpr int PK = BK + 8;  // padded LDS row (bf16)
  __shared__ bf16 As[BM * PK];
  __shared__ bf16 Bs[BN * PK];

  const int z = blockIdx.z;
  const bf16* Az = A + (long long)z * sAz;
  const bf16* Bz = Bw + (long long)z * sBz;
  const long long cofs = (long long)(z % HB) * sClo + (long long)(z / HB) * sChi;

  const int tid  = threadIdx.x;
  const int wave = tid >> 6;
  const int lane = tid & 63;
  const int lr   = lane & 15;
  const int kg   = lane >> 4;

  const int m0 = blockIdx.x * BM;
  const int n0 = blockIdx.y * BN;

  constexpr int FM = BM / 32;
  constexpr int FN = BN / 32;
  const int wm = (wave >> 1) * (BM / 2);
  const int wn = (wave & 1) * (BN / 2);

  f32x4 acc[FM][FN] = {};

  for (int kt = 0; kt < K; kt += BK) {
    // stage A tile [BM][64] (16B per thread-op, coalesced)
#pragma unroll
    for (int c = tid; c < BM * 8; c += 256) {
      const int r = c >> 3, ch = c & 7;
      *(uint4*)&As[r * PK + ch * 8] =
          *(const uint4*)&Az[(long long)(m0 + r) * lda + kt + ch * 8];
    }
    // stage B tile [BN][64]
#pragma unroll
    for (int c = tid; c < BN * 8; c += 256) {
      const int r = c >> 3, ch = c & 7;
      *(uint4*)&Bs[r * PK + ch * 8] =
          *(const uint4*)&Bz[(long long)(n0 + r) * ldb + kt + ch * 8];
    }
    __syncthreads();
#pragma unroll
    for (int ks = 0; ks < 2; ++ks) {
      bf16x8 af[FM], bq[FN];
#pragma unroll
      for (int i = 0; i < FM; ++i)
        af[i] = *(const bf16x8*)&As[(wm + i * 16 + lr) * PK + ks * 32 + kg * 8];
#pragma unroll
      for (int j = 0; j < FN; ++j)
        bq[j] = *(const bf16x8*)&Bs[(wn + j * 16 + lr) * PK + ks * 32 + kg * 8];
#pragma unroll
      for (int i = 0; i < FM; ++i)
#pragma unroll
        for (int j = 0; j < FN; ++j)
          acc[i][j] = mfma16(af[i], bq[j], acc[i][j]);
    }
    __syncthreads();
  }

  // epilogue: acc[i][j][r] -> row = wm+i*16+kg*4+r, col = wn+j*16+lr
#pragma unroll
  for (int i = 0; i < FM; ++i) {
#pragma unroll
    for (int j = 0; j < FN; ++j) {
      const int gc = n0 + wn + j * 16 + lr;
#pragma unroll
      for (int r = 0; r < 4; ++r) {
        const int gr = m0 + wm + i * 16 + kg * 4 + r;
        const float v = acc[i][j][r];
        if constexpr (EPI == 0) {
          ((bf16*)Cc + cofs)[(long long)gr * ldc + gc] = (bf16)v;
        } else if constexpr (EPI == 1) {
          ((float*)Cc + cofs)[(long long)gr * ldc + gc] = v * scale;
        } else if constexpr (EPI == 2) {
          float* p = (float*)Cc + (long long)gr * ldc + gc;
          *p += v + bias[gc];
        } else if constexpr (EPI == 3) {
          float t = v + bias[gc];
          t = 0.5f * t * (1.f + erff(t * 0.70710678118654752f));
          ((bf16*)Cc)[(long long)gr * ldc + gc] = (bf16)t;
        } else if constexpr (EPI == 4) {
          ((float*)Cc)[(long long)gr * ldc + gc] = v + bias[gc];
        } else if constexpr (EPI == 5) {
          const int bb = gr >> 9, ss = gr & 511, hh = gc >> 6, ee = gc & 63;
          ((bf16*)Cc)[(((long long)(bb * 8 + hh) * 512) + ss) * 64 + ee] = (bf16)v;
        } else if constexpr (EPI == 6) {
          const int bb = gr >> 9, ss = gr & 511, hh = gc >> 6, ee = gc & 63;
          ((bf16*)Cc)[(((long long)(bb * 8 + hh) * 64) + ee) * 512 + ss] = (bf16)v;
        }
      }
    }
  }
}

// ---------------------------------------------------------------------------
// Host orchestration
// ---------------------------------------------------------------------------
extern "C" void kernel_launch(void* const* d_in, const int* in_sizes, int n_in,
                              void* d_out, int out_size, void* d_ws, size_t ws_size,
                              hipStream_t stream)
{
  const int*   tok_src   = (const int*)d_in[0];
  const int*   tok_dst   = (const int*)d_in[1];
  const float* tok_emb   = (const float*)d_in[2];
  const float* pos_emb   = (const float*)d_in[3];
  const float* enc_ln1_w = (const float*)d_in[4];
  const float* enc_ln1_b = (const float*)d_in[5];
  const float* enc_wq    = (const float*)d_in[6];
  const float* enc_wk    = (const float*)d_in[7];
  const float* enc_wv    = (const float*)d_in[8];
  const float* enc_wo    = (const float*)d_in[9];
  const float* enc_bo    = (const float*)d_in[10];
  const float* enc_ln2_w = (const float*)d_in[11];
  const float* enc_ln2_b = (const float*)d_in[12];
  const float* enc_w1    = (const float*)d_in[13];
  const float* enc_b1    = (const float*)d_in[14];
  const float* enc_w2    = (const float*)d_in[15];
  const float* enc_b2    = (const float*)d_in[16];
  const float* enc_lnf_w = (const float*)d_in[17];
  const float* enc_lnf_b = (const float*)d_in[18];
  const float* dec_ln1_w = (const float*)d_in[19];
  const float* dec_ln1_b = (const float*)d_in[20];
  const float* dec_wq_s  = (const float*)d_in[21];
  const float* dec_wk_s  = (const float*)d_in[22];
  const float* dec_wv_s  = (const float*)d_in[23];
  const float* dec_wo_s  = (const float*)d_in[24];
  const float* dec_bo_s  = (const float*)d_in[25];
  const float* dec_ln2_w = (const float*)d_in[26];
  const float* dec_ln2_b = (const float*)d_in[27];
  const float* dec_wq_c  = (const float*)d_in[28];
  const float* dec_wk_c  = (const float*)d_in[29];
  const float* dec_wv_c  = (const float*)d_in[30];
  const float* dec_wo_c  = (const float*)d_in[31];
  const float* dec_bo_c  = (const float*)d_in[32];
  const float* dec_ln3_w = (const float*)d_in[33];
  const float* dec_ln3_b = (const float*)d_in[34];
  const float* dec_w1    = (const float*)d_in[35];
  const float* dec_b1    = (const float*)d_in[36];
  const float* dec_w2    = (const float*)d_in[37];
  const float* dec_b2    = (const float*)d_in[38];
  const float* dec_lnf_w = (const float*)d_in[39];
  const float* dec_lnf_b = (const float*)d_in[40];
  const float* head_w    = (const float*)d_in[41];
  const float* head_b    = (const float*)d_in[42];
  float* outp = (float*)d_out;

  // --- workspace bump allocator (total ~203 MB) ---
  char* wp = (char*)d_ws;
  auto alloc = [&](size_t nbytes) -> char* {
    char* p = wp; wp += (nbytes + 255) & ~(size_t)255; return p;
  };
  const size_t WQKV = (size_t)6 * 512 * 512 * 2;   // per-array qkv/wo bytes
  const size_t WFF  = (size_t)6 * 2048 * 512 * 2;  // per-array w1/w2 bytes

  bf16* tWq_e = (bf16*)alloc(WQKV);
  bf16* tWk_e = (bf16*)alloc(WQKV);
  bf16* tWv_e = (bf16*)alloc(WQKV);
  bf16* tWo_e = (bf16*)alloc(WQKV);
  bf16* tW1_e = (bf16*)alloc(WFF);
  bf16* tW2_e = (bf16*)alloc(WFF);
  bf16* tWq_s = (bf16*)alloc(WQKV);
  bf16* tWk_s = (bf16*)alloc(WQKV);
  bf16* tWv_s = (bf16*)alloc(WQKV);
  bf16* tWo_s = (bf16*)alloc(WQKV);
  bf16* tWq_c = (bf16*)alloc(WQKV);
  bf16* tWk_c = (bf16*)alloc(WQKV);
  bf16* tWv_c = (bf16*)alloc(WQKV);
  bf16* tWo_c = (bf16*)alloc(WQKV);
  bf16* tW1_d = (bf16*)alloc(WFF);
  bf16* tW2_d = (bf16*)alloc(WFF);
  bf16* tHead = (bf16*)alloc((size_t)32000 * 512 * 2);

  float* x   = (float*)alloc((size_t)2048 * 512 * 4);
  float* y   = (float*)alloc((size_t)2048 * 512 * 4);
  bf16*  h   = (bf16*)alloc((size_t)2048 * 512 * 2);
  bf16*  ql  = (bf16*)alloc((size_t)2048 * 512 * 2);  // [b,h][s][64]
  bf16*  kl  = (bf16*)alloc((size_t)2048 * 512 * 2);  // [b,h][t][64]
  bf16*  vt  = (bf16*)alloc((size_t)2048 * 512 * 2);  // [b,h][64][t]
  bf16*  xe  = (bf16*)alloc((size_t)2048 * 512 * 2);
  float* scb = (float*)alloc((size_t)32 * 512 * 512 * 4);
  bf16*  pbb = (bf16*)alloc((size_t)32 * 512 * 512 * 2);
  bf16*  ob  = (bf16*)alloc((size_t)2048 * 512 * 2);
  bf16*  h1  = (bf16*)alloc((size_t)2048 * 2048 * 2);
  bf16*  yd  = (bf16*)alloc((size_t)2048 * 512 * 2);

  const dim3 tb(32, 8);
  // --- pack (transpose+cast) all weights to bf16 [N][K] ---
  tcast_kernel<<<dim3(2, 16, 48), tb, 0, stream>>>(enc_wq, tWq_e, 512, 64);
  tcast_kernel<<<dim3(2, 16, 48), tb, 0, stream>>>(enc_wk, tWk_e, 512, 64);
  tcast_kernel<<<dim3(2, 16, 48), tb, 0, stream>>>(enc_wv, tWv_e, 512, 64);
  tcast_kernel<<<dim3(16, 16, 6), tb, 0, stream>>>(enc_wo, tWo_e, 512, 512);
  tcast_kernel<<<dim3(64, 16, 6), tb, 0, stream>>>(enc_w1, tW1_e, 512, 2048);
  tcast_kernel<<<dim3(16, 64, 6), tb, 0, stream>>>(enc_w2, tW2_e, 2048, 512);
  tcast_kernel<<<dim3(2, 16, 48), tb, 0, stream>>>(dec_wq_s, tWq_s, 512, 64);
  tcast_kernel<<<dim3(2, 16, 48), tb, 0, stream>>>(dec_wk_s, tWk_s, 512, 64);
  tcast_kernel<<<dim3(2, 16, 48), tb, 0, stream>>>(dec_wv_s, tWv_s, 512, 64);
  tcast_kernel<<<dim3(16, 16, 6), tb, 0, stream>>>(dec_wo_s, tWo_s, 512, 512);
  tcast_kernel<<<dim3(2, 16, 48), tb, 0, stream>>>(dec_wq_c, tWq_c, 512, 64);
  tcast_kernel<<<dim3(2, 16, 48), tb, 0, stream>>>(dec_wk_c, tWk_c, 512, 64);
  tcast_kernel<<<dim3(2, 16, 48), tb, 0, stream>>>(dec_wv_c, tWv_c, 512, 64);
  tcast_kernel<<<dim3(16, 16, 6), tb, 0, stream>>>(dec_wo_c, tWo_c, 512, 512);
  tcast_kernel<<<dim3(64, 16, 6), tb, 0, stream>>>(dec_w1, tW1_d, 512, 2048);
  tcast_kernel<<<dim3(16, 64, 6), tb, 0, stream>>>(dec_w2, tW2_d, 2048, 512);
  tcast_kernel<<<dim3(1000, 16, 1), tb, 0, stream>>>(head_w, tHead, 512, 32000);

  const long long SS = 512LL * 512;  // 262144

  // ---------------- encoder ----------------
  embed_kernel<<<2048, 128, 0, stream>>>(tok_src, tok_emb, pos_emb, x);
  for (int l = 0; l < 6; ++l) {
    ln_kernel<<<2048, 64, 0, stream>>>(x, enc_ln1_w + l * 512, enc_ln1_b + l * 512, h);
    gemm_kernel<64, 64, 5><<<dim3(32, 8, 1), 256, 0, stream>>>(
        h, tWq_e + (size_t)l * 262144, ql, nullptr, 512, 512, 512, 0, 0, 0, 0, 0, 1, 1.f);
    gemm_kernel<64, 64, 5><<<dim3(32, 8, 1), 256, 0, stream>>>(
        h, tWk_e + (size_t)l * 262144, kl, nullptr, 512, 512, 512, 0, 0, 0, 0, 0, 1, 1.f);
    gemm_kernel<64, 64, 6><<<dim3(32, 8, 1), 256, 0, stream>>>(
        h, tWv_e + (size_t)l * 262144, vt, nullptr, 512, 512, 512, 0, 0, 0, 0, 0, 1, 1.f);
    gemm_kernel<128, 128, 1><<<dim3(4, 4, 32), 256, 0, stream>>>(
        ql, kl, scb, nullptr, 64, 64, 64, 512, 32768, 32768, 0, SS, 1, 0.125f);
    softmax_kernel<0><<<16384, 64, 0, stream>>>(scb, pbb, tok_src);
    gemm_kernel<64, 64, 0><<<dim3(8, 1, 32), 256, 0, stream>>>(
        pbb, vt, ob, nullptr, 512, 512, 512, 512, SS, 32768, 64, SS, 8, 1.f);
    gemm_kernel<64, 64, 2><<<dim3(32, 8, 1), 256, 0, stream>>>(
        ob, tWo_e + (size_t)l * 262144, x, enc_bo + l * 512, 512, 512, 512, 512, 0, 0, 0, 0, 1, 1.f);
    ln_kernel<<<2048, 64, 0, stream>>>(x, enc_ln2_w + l * 512, enc_ln2_b + l * 512, h);
    gemm_kernel<128, 128, 3><<<dim3(16, 16, 1), 256, 0, stream>>>(
        h, tW1_e + (size_t)l * 1048576, h1, enc_b1 + l * 2048, 512, 512, 512, 2048, 0, 0, 0, 0, 1, 1.f);
    gemm_kernel<64, 64, 2><<<dim3(32, 8, 1), 256, 0, stream>>>(
        h1, tW2_e + (size_t)l * 1048576, x, enc_b2 + l * 512, 2048, 2048, 2048, 512, 0, 0, 0, 0, 1, 1.f);
  }
  ln_kernel<<<2048, 64, 0, stream>>>(x, enc_lnf_w, enc_lnf_b, xe);

  // ---------------- decoder ----------------
  embed_kernel<<<2048, 128, 0, stream>>>(tok_dst, tok_emb, pos_emb, y);
  for (int l = 0; l < 6; ++l) {
    // self-attention (causal)
    ln_kernel<<<2048, 64, 0, stream>>>(y, dec_ln1_w + l * 512, dec_ln1_b + l * 512, h);
    gemm_kernel<64, 64, 5><<<dim3(32, 8, 1), 256, 0, stream>>>(
        h, tWq_s + (size_t)l * 262144, ql, nullptr, 512, 512, 512, 0, 0, 0, 0, 0, 1, 1.f);
    gemm_kernel<64, 64, 5><<<dim3(32, 8, 1), 256, 0, stream>>>(
        h, tWk_s + (size_t)l * 262144, kl, nullptr, 512, 512, 512, 0, 0, 0, 0, 0, 1, 1.f);
    gemm_kernel<64, 64, 6><<<dim3(32, 8, 1), 256, 0, stream>>>(
        h, tWv_s + (size_t)l * 262144, vt, nullptr, 512, 512, 512, 0, 0, 0, 0, 0, 1, 1.f);
    gemm_kernel<128, 128, 1><<<dim3(4, 4, 32), 256, 0, stream>>>(
        ql, kl, scb, nullptr, 64, 64, 64, 512, 32768, 32768, 0, SS, 1, 0.125f);
    softmax_kernel<1><<<16384, 64, 0, stream>>>(scb, pbb, nullptr);
    gemm_kernel<64, 64, 0><<<dim3(8, 1, 32), 256, 0, stream>>>(
        pbb, vt, ob, nullptr, 512, 512, 512, 512, SS, 32768, 64, SS, 8, 1.f);
    gemm_kernel<64, 64, 2><<<dim3(32, 8, 1), 256, 0, stream>>>(
        ob, tWo_s + (size_t)l * 262144, y, dec_bo_s + l * 512, 512, 512, 512, 512, 0, 0, 0, 0, 1, 1.f);
    // cross-attention (keys/values from encoder output xe, key mask)
    ln_kernel<<<2048, 64, 0, stream>>>(y, dec_ln2_w + l * 512, dec_ln2_b + l * 512, h);
    gemm_kernel<64, 64, 5><<<dim3(32, 8, 1), 256, 0, stream>>>(
        h, tWq_c + (size_t)l * 262144, ql, nullptr, 512, 512, 512, 0, 0, 0, 0, 0, 1, 1.f);
    gemm_kernel<64, 64, 5><<<dim3(32, 8, 1), 256, 0, stream>>>(
        xe, tWk_c + (size_t)l * 262144, kl, nullptr, 512, 512, 512, 0, 0, 0, 0, 0, 1, 1.f);
    gemm_kernel<64, 64, 6><<<dim3(32, 8, 1), 256, 0, stream>>>(
        xe, tWv_c + (size_t)l * 262144, vt, nullptr, 512, 512, 512, 0, 0, 0, 0, 0, 1, 1.f);
    gemm_kernel<128, 128, 1><<<dim3(4, 4, 32), 256, 0, stream>>>(
        ql, kl, scb, nullptr, 64, 64, 64, 512, 32768, 32768, 0, SS, 1, 0.125f);
    softmax_kernel<0><<<16384, 64, 0, stream>>>(scb, pbb, tok_src);
    gemm_kernel<64, 64, 0><<<dim3(8, 1, 32), 256, 0, stream>>>(
        pbb, vt, ob, nullptr, 512, 512, 512, 512, SS, 32768, 64, SS, 8, 1.f);
    gemm_kernel<64, 64, 2><<<dim3(32, 8, 1), 256, 0, stream>>>(
        ob, tWo_c + (size_t)l * 262144, y, dec_bo_c + l * 512, 512, 512, 512, 512, 0, 0, 0, 0, 1, 1.f);
    // FFN
    ln_kernel<<<2048, 64, 0, stream>>>(y, dec_ln3_w + l * 512, dec_ln3_b + l * 512, h);
    gemm_kernel<128, 128, 3><<<dim3(16, 16, 1), 256, 0, stream>>>(
        h, tW1_d + (size_t)l * 1048576, h1, dec_b1 + l * 2048, 512, 512, 512, 2048, 0, 0, 0, 0, 1, 1.f);
    gemm_kernel<64, 64, 2><<<dim3(32, 8, 1), 256, 0, stream>>>(
        h1, tW2_d + (size_t)l * 1048576, y, dec_b2 + l * 512, 2048, 2048, 2048, 512, 0, 0, 0, 0, 1, 1.f);
  }
  ln_kernel<<<2048, 64, 0, stream>>>(y, dec_lnf_w, dec_lnf_b, yd);
  // head: logits [2048, 32000] fp32
  gemm_kernel<128, 128, 4><<<dim3(16, 250, 1), 256, 0, stream>>>(
      yd, tHead, outp, head_b, 512, 512, 512, 32000, 0, 0, 0, 0, 1, 1.f);
}

// Round 2
// 2544.446 us; speedup vs baseline: 1.3952x; 1.3952x over previous
//
#include <hip/hip_runtime.h>
#include <math.h>

// ---------------------------------------------------------------------------
// SimpleTranslate encoder-decoder forward, MI355X/gfx950.
// Round 1: m97-style GEMM (global_load_lds width-16, linear LDS, 2-barrier
// loop), QKV fusion (N=1536 self / N=1024 cross-KV). bf16 MFMA 16x16x32,
// fp32 accumulate; LN/softmax/residual fp32.
// ---------------------------------------------------------------------------

typedef __bf16 bf16;
typedef bf16  bf16x8 __attribute__((ext_vector_type(8)));
typedef float f32x4  __attribute__((ext_vector_type(4)));

#define DEV __device__ __forceinline__

DEV f32x4 mfma16(bf16x8 a, bf16x8 b, f32x4 c) {
  return __builtin_amdgcn_mfma_f32_16x16x32_bf16(a, b, c, 0, 0, 0);
}

// async global->LDS, 16 B per lane (dest must be linear: wave base + lane*16)
DEV void async_copy16(const bf16* g, bf16* l) {
  __builtin_amdgcn_global_load_lds(
      (__attribute__((address_space(1))) void*)(g),
      (__attribute__((address_space(3))) void*)(l), 16, 0, 0);
}

// ---------------------------------------------------------------------------
// Transpose + fp32->bf16 cast: in [Z][R][C] f32 -> out [C][R] bf16 blocks at
// zo = (z/zdiv)*oHi + (z%zdiv)*oLo + oOfs.   block (32,8), grid (C/32,R/32,Z)
// ---------------------------------------------------------------------------
__global__ __launch_bounds__(256) void tcast_kernel(
    const float* __restrict__ in, bf16* __restrict__ out, const int R, const int C,
    const long long oHi, const long long oLo, const int zdiv, const long long oOfs)
{
  __shared__ float tile[32][33];
  const int z = blockIdx.z;
  const long long zi = (long long)z * R * C;
  const long long zo = (long long)(z / zdiv) * oHi + (long long)(z % zdiv) * oLo + oOfs;
  const int c0 = blockIdx.x * 32, r0 = blockIdx.y * 32;
  const int tx = threadIdx.x, ty = threadIdx.y;
#pragma unroll
  for (int i = 0; i < 32; i += 8)
    tile[ty + i][tx] = in[zi + (long long)(r0 + ty + i) * C + c0 + tx];
  __syncthreads();
#pragma unroll
  for (int i = 0; i < 32; i += 8)
    out[zo + (long long)(c0 + ty + i) * R + r0 + tx] = (bf16)tile[tx][ty + i];
}

// ---------------------------------------------------------------------------
// Embedding: x[row,:] = tok_emb[tok[row],:] + pos_emb[row%512,:]  (fp32)
// ---------------------------------------------------------------------------
__global__ __launch_bounds__(128) void embed_kernel(
    const int* __restrict__ tok, const float* __restrict__ temb,
    const float* __restrict__ pemb, float* __restrict__ x)
{
  const int row  = blockIdx.x;
  const int sPos = row & 511;
  const int t    = tok[row];
  const int d    = threadIdx.x * 4;
  f32x4 a = *(const f32x4*)&temb[(long long)t * 512 + d];
  f32x4 p = *(const f32x4*)&pemb[(long long)sPos * 512 + d];
  *(f32x4*)&x[(long long)row * 512 + d] = a + p;
}

// ---------------------------------------------------------------------------
// LayerNorm row of 512, fp32 in, bf16 out. One wave per row.
// ---------------------------------------------------------------------------
__global__ __launch_bounds__(64) void ln_kernel(
    const float* __restrict__ x, const float* __restrict__ w,
    const float* __restrict__ b, bf16* __restrict__ out)
{
  const int row = blockIdx.x;
  const int lane = threadIdx.x;
  const float* xr = x + (long long)row * 512;
  f32x4 a0 = *(const f32x4*)&xr[lane * 8];
  f32x4 a1 = *(const f32x4*)&xr[lane * 8 + 4];
  float s = 0.f, q = 0.f;
#pragma unroll
  for (int k = 0; k < 4; ++k) { s += a0[k] + a1[k]; q += a0[k]*a0[k] + a1[k]*a1[k]; }
#pragma unroll
  for (int m = 1; m < 64; m <<= 1) { s += __shfl_xor(s, m); q += __shfl_xor(q, m); }
  const float mean = s * (1.f / 512.f);
  const float var  = q * (1.f / 512.f) - mean * mean;
  const float rs   = rsqrtf(var + 1e-5f);
  f32x4 w0 = *(const f32x4*)&w[lane * 8], w1 = *(const f32x4*)&w[lane * 8 + 4];
  f32x4 b0 = *(const f32x4*)&b[lane * 8], b1 = *(const f32x4*)&b[lane * 8 + 4];
  bf16x8 o;
#pragma unroll
  for (int k = 0; k < 4; ++k) {
    o[k]     = (bf16)((a0[k] - mean) * rs * w0[k] + b0[k]);
    o[k + 4] = (bf16)((a1[k] - mean) * rs * w1[k] + b1[k]);
  }
  *(bf16x8*)&out[(long long)row * 512 + lane * 8] = o;
}

// ---------------------------------------------------------------------------
// Masked softmax rows of 512 fp32 -> bf16. MODE 0: key mask; MODE 1: causal.
// ---------------------------------------------------------------------------
template <int MODE>
__global__ __launch_bounds__(64) void softmax_kernel(
    const float* __restrict__ sc, bf16* __restrict__ pb,
    const int* __restrict__ srctok)
{
  const int row  = blockIdx.x;
  const int sPos = row & 511;
  const int b    = row >> 12;
  const int lane = threadIdx.x;
  const float* sr = sc + (long long)row * 512;
  f32x4 va = *(const f32x4*)&sr[lane * 8];
  f32x4 vb = *(const f32x4*)&sr[lane * 8 + 4];
  float v[8] = { va[0], va[1], va[2], va[3], vb[0], vb[1], vb[2], vb[3] };
  bool ok[8];
  if (MODE == 0) {
    const int* tk = srctok + b * 512 + lane * 8;
#pragma unroll
    for (int i = 0; i < 8; ++i) ok[i] = (tk[i] != 0);
  } else {
#pragma unroll
    for (int i = 0; i < 8; ++i) ok[i] = (lane * 8 + i) <= sPos;
  }
  float mx = -3.0e38f;
#pragma unroll
  for (int i = 0; i < 8; ++i) if (ok[i]) mx = fmaxf(mx, v[i]);
#pragma unroll
  for (int m = 1; m < 64; m <<= 1) mx = fmaxf(mx, __shfl_xor(mx, m));
  float e[8]; float sum = 0.f;
#pragma unroll
  for (int i = 0; i < 8; ++i) { e[i] = ok[i] ? __expf(v[i] - mx) : 0.f; sum += e[i]; }
#pragma unroll
  for (int m = 1; m < 64; m <<= 1) sum += __shfl_xor(sum, m);
  const float inv = 1.f / sum;
  bf16x8 o;
#pragma unroll
  for (int i = 0; i < 8; ++i) o[i] = (bf16)(e[i] * inv);
  *(bf16x8*)&pb[(long long)row * 512 + lane * 8] = o;
}

// ---------------------------------------------------------------------------
// bf16 MFMA GEMM, m97 structure. C[M,N] = A[M,K] * B^T (B given [N][K]).
// 256 threads / 4 waves (2x2); BK=64; LDS linear; global_load_lds dwordx4.
// Epilogues:
//  0: C bf16 = v                      (PV: cofs + [s][512] at col h*64+e)
//  1: C f32  = v*scale                (scores)
//  2: C f32 += v + bias[col]          (residual add: WO / FFN2)
//  3: C bf16 = gelu(v + bias[col])    (FFN1)
//  4: C f32  = v + bias[col]          (head logits)
//  7: qkv scatter, sel = (col>>9)+selofs (passed in sClo):
//     sel 0/1 (q/k): [(b*8+h)*512+s][64]; sel 2 (v, transposed): [(b*8+h)*64+e][512]
// ---------------------------------------------------------------------------
template <int BM, int BN, int EPI>
__global__ __launch_bounds__(256) void gemm_kernel(
    const bf16* __restrict__ A, const bf16* __restrict__ Bw,
    void* __restrict__ Cc, const float* __restrict__ bias,
    const int K, const int lda, const int ldb, const int ldc,
    const long long sAz, const long long sBz,
    const long long sClo, const long long sChi, const int HB,
    const float scale)
{
  constexpr int BK = 64;
  __shared__ bf16 As[BM * BK];
  __shared__ bf16 Bs[BN * BK];
  constexpr int AISS = (BM * BK * 2) / 4096;  // 16B x 256 threads per issue
  constexpr int BISS = (BN * BK * 2) / 4096;

  const int z = blockIdx.z;
  const bf16* Az = A + (long long)z * sAz;
  const bf16* Bz = Bw + (long long)z * sBz;
  const long long cofs = (long long)(z % HB) * sClo + (long long)(z / HB) * sChi;

  const int tid  = threadIdx.x;
  const int wave = tid >> 6;
  const int lane = tid & 63;
  const int lr   = lane & 15;
  const int kg   = lane >> 4;

  const int m0 = blockIdx.x * BM;
  const int n0 = blockIdx.y * BN;

  constexpr int FM = BM / 32;
  constexpr int FN = BN / 32;
  const int wm = (wave >> 1) * (BM / 2);
  const int wn = (wave & 1) * (BN / 2);

  f32x4 acc[FM][FN] = {};

  for (int kt = 0; kt < K; kt += BK) {
#pragma unroll
    for (int i = 0; i < AISS; ++i) {
      const int o = i * 4096 + tid * 16;   // byte offset in As
      const int r = o >> 7;                // 128 B per row
      const int c = (o & 127) >> 1;
      async_copy16(Az + (long long)(m0 + r) * lda + kt + c, (bf16*)((char*)As + o));
    }
#pragma unroll
    for (int i = 0; i < BISS; ++i) {
      const int o = i * 4096 + tid * 16;
      const int r = o >> 7;
      const int c = (o & 127) >> 1;
      async_copy16(Bz + (long long)(n0 + r) * ldb + kt + c, (bf16*)((char*)Bs + o));
    }
    __syncthreads();
#pragma unroll
    for (int ks = 0; ks < 2; ++ks) {
      bf16x8 af[FM], bq[FN];
#pragma unroll
      for (int i = 0; i < FM; ++i)
        af[i] = *(const bf16x8*)&As[(wm + i * 16 + lr) * BK + ks * 32 + kg * 8];
#pragma unroll
      for (int j = 0; j < FN; ++j)
        bq[j] = *(const bf16x8*)&Bs[(wn + j * 16 + lr) * BK + ks * 32 + kg * 8];
#pragma unroll
      for (int i = 0; i < FM; ++i)
#pragma unroll
        for (int j = 0; j < FN; ++j)
          acc[i][j] = mfma16(af[i], bq[j], acc[i][j]);
    }
    __syncthreads();
  }

  // epilogue: acc[i][j][r] -> row = wm+i*16+kg*4+r, col = wn+j*16+lr
#pragma unroll
  for (int i = 0; i < FM; ++i) {
#pragma unroll
    for (int j = 0; j < FN; ++j) {
      const int gc = n0 + wn + j * 16 + lr;
#pragma unroll
      for (int r = 0; r < 4; ++r) {
        const int gr = m0 + wm + i * 16 + kg * 4 + r;
        const float v = acc[i][j][r];
        if constexpr (EPI == 0) {
          ((bf16*)Cc + cofs)[(long long)gr * ldc + gc] = (bf16)v;
        } else if constexpr (EPI == 1) {
          ((float*)Cc + cofs)[(long long)gr * ldc + gc] = v * scale;
        } else if constexpr (EPI == 2) {
          float* p = (float*)Cc + (long long)gr * ldc + gc;
          *p += v + bias[gc];
        } else if constexpr (EPI == 3) {
          float t = v + bias[gc];
          t = 0.5f * t * (1.f + erff(t * 0.70710678118654752f));
          ((bf16*)Cc)[(long long)gr * ldc + gc] = (bf16)t;
        } else if constexpr (EPI == 4) {
          ((float*)Cc)[(long long)gr * ldc + gc] = v + bias[gc];
        } else if constexpr (EPI == 7) {
          const int sel = (gc >> 9) + (int)sClo;
          const int hh = (gc >> 6) & 7, ee = gc & 63;
          const int bb = gr >> 9, ss = gr & 511;
          bf16* base = (bf16*)Cc + (long long)sel * (2048 * 512);
          if (sel < 2) base[(((long long)(bb * 8 + hh) << 9) + ss) * 64 + ee] = (bf16)v;
          else         base[(((long long)(bb * 8 + hh) << 6) + ee) * 512 + ss] = (bf16)v;
        }
      }
    }
  }
}

// ---------------------------------------------------------------------------
// Host orchestration
// ---------------------------------------------------------------------------
extern "C" void kernel_launch(void* const* d_in, const int* in_sizes, int n_in,
                              void* d_out, int out_size, void* d_ws, size_t ws_size,
                              hipStream_t stream)
{
  const int*   tok_src   = (const int*)d_in[0];
  const int*   tok_dst   = (const int*)d_in[1];
  const float* tok_emb   = (const float*)d_in[2];
  const float* pos_emb   = (const float*)d_in[3];
  const float* enc_ln1_w = (const float*)d_in[4];
  const float* enc_ln1_b = (const float*)d_in[5];
  const float* enc_wq    = (const float*)d_in[6];
  const float* enc_wk    = (const float*)d_in[7];
  const float* enc_wv    = (const float*)d_in[8];
  const float* enc_wo    = (const float*)d_in[9];
  const float* enc_bo    = (const float*)d_in[10];
  const float* enc_ln2_w = (const float*)d_in[11];
  const float* enc_ln2_b = (const float*)d_in[12];
  const float* enc_w1    = (const float*)d_in[13];
  const float* enc_b1    = (const float*)d_in[14];
  const float* enc_w2    = (const float*)d_in[15];
  const float* enc_b2    = (const float*)d_in[16];
  const float* enc_lnf_w = (const float*)d_in[17];
  const float* enc_lnf_b = (const float*)d_in[18];
  const float* dec_ln1_w = (const float*)d_in[19];
  const float* dec_ln1_b = (const float*)d_in[20];
  const float* dec_wq_s  = (const float*)d_in[21];
  const float* dec_wk_s  = (const float*)d_in[22];
  const float* dec_wv_s  = (const float*)d_in[23];
  const float* dec_wo_s  = (const float*)d_in[24];
  const float* dec_bo_s  = (const float*)d_in[25];
  const float* dec_ln2_w = (const float*)d_in[26];
  const float* dec_ln2_b = (const float*)d_in[27];
  const float* dec_wq_c  = (const float*)d_in[28];
  const float* dec_wk_c  = (const float*)d_in[29];
  const float* dec_wv_c  = (const float*)d_in[30];
  const float* dec_wo_c  = (const float*)d_in[31];
  const float* dec_bo_c  = (const float*)d_in[32];
  const float* dec_ln3_w = (const float*)d_in[33];
  const float* dec_ln3_b = (const float*)d_in[34];
  const float* dec_w1    = (const float*)d_in[35];
  const float* dec_b1    = (const float*)d_in[36];
  const float* dec_w2    = (const float*)d_in[37];
  const float* dec_b2    = (const float*)d_in[38];
  const float* dec_lnf_w = (const float*)d_in[39];
  const float* dec_lnf_b = (const float*)d_in[40];
  const float* head_w    = (const float*)d_in[41];
  const float* head_b    = (const float*)d_in[42];
  float* outp = (float*)d_out;

  // --- workspace bump allocator ---
  char* wp = (char*)d_ws;
  auto alloc = [&](size_t nbytes) -> char* {
    char* p = wp; wp += (nbytes + 255) & ~(size_t)255; return p;
  };
  const long long LQKV = 1536LL * 512;            // per-layer fused qkv rows
  const long long LKV  = 1024LL * 512;
  const long long LSQ  = 512LL * 512;
  const long long LFF  = 2048LL * 512;

  bf16* tQKV_e = (bf16*)alloc((size_t)6 * LQKV * 2);
  bf16* tQKV_s = (bf16*)alloc((size_t)6 * LQKV * 2);
  bf16* tQ_c   = (bf16*)alloc((size_t)6 * LSQ * 2);
  bf16* tKV_c  = (bf16*)alloc((size_t)6 * LKV * 2);
  bf16* tWo_e  = (bf16*)alloc((size_t)6 * LSQ * 2);
  bf16* tWo_s  = (bf16*)alloc((size_t)6 * LSQ * 2);
  bf16* tWo_c  = (bf16*)alloc((size_t)6 * LSQ * 2);
  bf16* tW1_e  = (bf16*)alloc((size_t)6 * LFF * 2);
  bf16* tW2_e  = (bf16*)alloc((size_t)6 * LFF * 2);
  bf16* tW1_d  = (bf16*)alloc((size_t)6 * LFF * 2);
  bf16* tW2_d  = (bf16*)alloc((size_t)6 * LFF * 2);
  bf16* tHead  = (bf16*)alloc((size_t)32000 * 512 * 2);

  float* x   = (float*)alloc((size_t)2048 * 512 * 4);
  float* y   = (float*)alloc((size_t)2048 * 512 * 4);
  bf16*  h   = (bf16*)alloc((size_t)2048 * 512 * 2);
  bf16*  qkv = (bf16*)alloc((size_t)3 * 2048 * 512 * 2);  // q | k | v^T sections
  bf16*  xe  = (bf16*)alloc((size_t)2048 * 512 * 2);
  float* scb = (float*)alloc((size_t)32 * 512 * 512 * 4);
  bf16*  pbb = (bf16*)alloc((size_t)32 * 512 * 512 * 2);
  bf16*  ob  = (bf16*)alloc((size_t)2048 * 512 * 2);
  bf16*  h1  = (bf16*)alloc((size_t)2048 * 2048 * 2);
  bf16*  yd  = (bf16*)alloc((size_t)2048 * 512 * 2);

  bf16* ql = qkv;
  bf16* kl = qkv + 2048 * 512;
  bf16* vt = qkv + 2 * 2048 * 512;

  const dim3 tb(32, 8);
  // --- pack weights to bf16 [N][K] ---
  // fused self-qkv: in [6][8][512][64] (Z=48) -> [6][1536][512]
  tcast_kernel<<<dim3(2, 16, 48), tb, 0, stream>>>(enc_wq, tQKV_e, 512, 64, LQKV, 32768, 8, 0);
  tcast_kernel<<<dim3(2, 16, 48), tb, 0, stream>>>(enc_wk, tQKV_e, 512, 64, LQKV, 32768, 8, 262144);
  tcast_kernel<<<dim3(2, 16, 48), tb, 0, stream>>>(enc_wv, tQKV_e, 512, 64, LQKV, 32768, 8, 524288);
  tcast_kernel<<<dim3(2, 16, 48), tb, 0, stream>>>(dec_wq_s, tQKV_s, 512, 64, LQKV, 32768, 8, 0);
  tcast_kernel<<<dim3(2, 16, 48), tb, 0, stream>>>(dec_wk_s, tQKV_s, 512, 64, LQKV, 32768, 8, 262144);
  tcast_kernel<<<dim3(2, 16, 48), tb, 0, stream>>>(dec_wv_s, tQKV_s, 512, 64, LQKV, 32768, 8, 524288);
  tcast_kernel<<<dim3(2, 16, 48), tb, 0, stream>>>(dec_wq_c, tQ_c, 512, 64, LSQ, 32768, 8, 0);
  tcast_kernel<<<dim3(2, 16, 48), tb, 0, stream>>>(dec_wk_c, tKV_c, 512, 64, LKV, 32768, 8, 0);
  tcast_kernel<<<dim3(2, 16, 48), tb, 0, stream>>>(dec_wv_c, tKV_c, 512, 64, LKV, 32768, 8, 262144);
  tcast_kernel<<<dim3(16, 16, 6), tb, 0, stream>>>(enc_wo, tWo_e, 512, 512, LSQ, 0, 1, 0);
  tcast_kernel<<<dim3(16, 16, 6), tb, 0, stream>>>(dec_wo_s, tWo_s, 512, 512, LSQ, 0, 1, 0);
  tcast_kernel<<<dim3(16, 16, 6), tb, 0, stream>>>(dec_wo_c, tWo_c, 512, 512, LSQ, 0, 1, 0);
  tcast_kernel<<<dim3(64, 16, 6), tb, 0, stream>>>(enc_w1, tW1_e, 512, 2048, LFF, 0, 1, 0);
  tcast_kernel<<<dim3(16, 64, 6), tb, 0, stream>>>(enc_w2, tW2_e, 2048, 512, LFF, 0, 1, 0);
  tcast_kernel<<<dim3(64, 16, 6), tb, 0, stream>>>(dec_w1, tW1_d, 512, 2048, LFF, 0, 1, 0);
  tcast_kernel<<<dim3(16, 64, 6), tb, 0, stream>>>(dec_w2, tW2_d, 2048, 512, LFF, 0, 1, 0);
  tcast_kernel<<<dim3(1000, 16, 1), tb, 0, stream>>>(head_w, tHead, 512, 32000, 0, 0, 1, 0);

  const long long SS = 512LL * 512;

  // ---------------- encoder ----------------
  embed_kernel<<<2048, 128, 0, stream>>>(tok_src, tok_emb, pos_emb, x);
  for (int l = 0; l < 6; ++l) {
    ln_kernel<<<2048, 64, 0, stream>>>(x, enc_ln1_w + l * 512, enc_ln1_b + l * 512, h);
    gemm_kernel<128, 128, 7><<<dim3(16, 12, 1), 256, 0, stream>>>(
        h, tQKV_e + (size_t)l * LQKV, qkv, nullptr, 512, 512, 512, 0, 0, 0, 0, 0, 1, 1.f);
    gemm_kernel<128, 128, 1><<<dim3(4, 4, 32), 256, 0, stream>>>(
        ql, kl, scb, nullptr, 64, 64, 64, 512, 32768, 32768, 0, SS, 1, 0.125f);
    softmax_kernel<0><<<16384, 64, 0, stream>>>(scb, pbb, tok_src);
    gemm_kernel<64, 64, 0><<<dim3(8, 1, 32), 256, 0, stream>>>(
        pbb, vt, ob, nullptr, 512, 512, 512, 512, SS, 32768, 64, SS, 8, 1.f);
    gemm_kernel<64, 64, 2><<<dim3(32, 8, 1), 256, 0, stream>>>(
        ob, tWo_e + (size_t)l * LSQ, x, enc_bo + l * 512, 512, 512, 512, 512, 0, 0, 0, 0, 1, 1.f);
    ln_kernel<<<2048, 64, 0, stream>>>(x, enc_ln2_w + l * 512, enc_ln2_b + l * 512, h);
    gemm_kernel<128, 128, 3><<<dim3(16, 16, 1), 256, 0, stream>>>(
        h, tW1_e + (size_t)l * LFF, h1, enc_b1 + l * 2048, 512, 512, 512, 2048, 0, 0, 0, 0, 1, 1.f);
    gemm_kernel<64, 64, 2><<<dim3(32, 8, 1), 256, 0, stream>>>(
        h1, tW2_e + (size_t)l * LFF, x, enc_b2 + l * 512, 2048, 2048, 2048, 512, 0, 0, 0, 0, 1, 1.f);
  }
  ln_kernel<<<2048, 64, 0, stream>>>(x, enc_lnf_w, enc_lnf_b, xe);

  // ---------------- decoder ----------------
  embed_kernel<<<2048, 128, 0, stream>>>(tok_dst, tok_emb, pos_emb, y);
  for (int l = 0; l < 6; ++l) {
    // self-attention (causal)
    ln_kernel<<<2048, 64, 0, stream>>>(y, dec_ln1_w + l * 512, dec_ln1_b + l * 512, h);
    gemm_kernel<128, 128, 7><<<dim3(16, 12, 1), 256, 0, stream>>>(
        h, tQKV_s + (size_t)l * LQKV, qkv, nullptr, 512, 512, 512, 0, 0, 0, 0, 0, 1, 1.f);
    gemm_kernel<128, 128, 1><<<dim3(4, 4, 32), 256, 0, stream>>>(
        ql, kl, scb, nullptr, 64, 64, 64, 512, 32768, 32768, 0, SS, 1, 0.125f);
    softmax_kernel<1><<<16384, 64, 0, stream>>>(scb, pbb, nullptr);
    gemm_kernel<64, 64, 0><<<dim3(8, 1, 32), 256, 0, stream>>>(
        pbb, vt, ob, nullptr, 512, 512, 512, 512, SS, 32768, 64, SS, 8, 1.f);
    gemm_kernel<64, 64, 2><<<dim3(32, 8, 1), 256, 0, stream>>>(
        ob, tWo_s + (size_t)l * LSQ, y, dec_bo_s + l * 512, 512, 512, 512, 512, 0, 0, 0, 0, 1, 1.f);
    // cross-attention (K/V from encoder output xe, key mask)
    ln_kernel<<<2048, 64, 0, stream>>>(y, dec_ln2_w + l * 512, dec_ln2_b + l * 512, h);
    gemm_kernel<64, 64, 7><<<dim3(32, 8, 1), 256, 0, stream>>>(
        h, tQ_c + (size_t)l * LSQ, qkv, nullptr, 512, 512, 512, 0, 0, 0, 0, 0, 1, 1.f);
    gemm_kernel<64, 64, 7><<<dim3(32, 16, 1), 256, 0, stream>>>(
        xe, tKV_c + (size_t)l * LKV, qkv, nullptr, 512, 512, 512, 0, 0, 0, 1, 0, 1, 1.f);
    gemm_kernel<128, 128, 1><<<dim3(4, 4, 32), 256, 0, stream>>>(
        ql, kl, scb, nullptr, 64, 64, 64, 512, 32768, 32768, 0, SS, 1, 0.125f);
    softmax_kernel<0><<<16384, 64, 0, stream>>>(scb, pbb, tok_src);
    gemm_kernel<64, 64, 0><<<dim3(8, 1, 32), 256, 0, stream>>>(
        pbb, vt, ob, nullptr, 512, 512, 512, 512, SS, 32768, 64, SS, 8, 1.f);
    gemm_kernel<64, 64, 2><<<dim3(32, 8, 1), 256, 0, stream>>>(
        ob, tWo_c + (size_t)l * LSQ, y, dec_bo_c + l * 512, 512, 512, 512, 512, 0, 0, 0, 0, 1, 1.f);
    // FFN
    ln_kernel<<<2048, 64, 0, stream>>>(y, dec_ln3_w + l * 512, dec_ln3_b + l * 512, h);
    gemm_kernel<128, 128, 3><<<dim3(16, 16, 1), 256, 0, stream>>>(
        h, tW1_d + (size_t)l * LFF, h1, dec_b1 + l * 2048, 512, 512, 512, 2048, 0, 0, 0, 0, 1, 1.f);
    gemm_kernel<64, 64, 2><<<dim3(32, 8, 1), 256, 0, stream>>>(
        h1, tW2_d + (size_t)l * LFF, y, dec_b2 + l * 512, 2048, 2048, 2048, 512, 0, 0, 0, 0, 1, 1.f);
  }
  ln_kernel<<<2048, 64, 0, stream>>>(y, dec_lnf_w, dec_lnf_b, yd);
  // head: logits [2048, 32000] fp32
  gemm_kernel<128, 128, 4><<<dim3(16, 250, 1), 256, 0, stream>>>(
      yd, tHead, outp, head_b, 512, 512, 512, 32000, 0, 0, 0, 0, 1, 1.f);
}

// Round 3
// 2366.068 us; speedup vs baseline: 1.5004x; 1.0754x over previous
//
#include <hip/hip_runtime.h>
#include <math.h>

// ---------------------------------------------------------------------------
// SimpleTranslate encoder-decoder forward, MI355X/gfx950.
// Round 2: fused flash-attention (online softmax, per-wave state) + fused
// residual-add+LN. GEMMs keep the m97 structure (global_load_lds width-16).
// ---------------------------------------------------------------------------

typedef __bf16 bf16;
typedef bf16  bf16x8 __attribute__((ext_vector_type(8)));
typedef float f32x4  __attribute__((ext_vector_type(4)));

#define DEV __device__ __forceinline__

DEV f32x4 mfma16(bf16x8 a, bf16x8 b, f32x4 c) {
  return __builtin_amdgcn_mfma_f32_16x16x32_bf16(a, b, c, 0, 0, 0);
}

DEV void async_copy16(const bf16* g, bf16* l) {
  __builtin_amdgcn_global_load_lds(
      (__attribute__((address_space(1))) void*)(g),
      (__attribute__((address_space(3))) void*)(l), 16, 0, 0);
}

// ---------------------------------------------------------------------------
// Transpose + fp32->bf16 cast: in [Z][R][C] f32 -> out [C][R] bf16 blocks at
// zo = (z/zdiv)*oHi + (z%zdiv)*oLo + oOfs.   block (32,8), grid (C/32,R/32,Z)
// ---------------------------------------------------------------------------
__global__ __launch_bounds__(256) void tcast_kernel(
    const float* __restrict__ in, bf16* __restrict__ out, const int R, const int C,
    const long long oHi, const long long oLo, const int zdiv, const long long oOfs)
{
  __shared__ float tile[32][33];
  const int z = blockIdx.z;
  const long long zi = (long long)z * R * C;
  const long long zo = (long long)(z / zdiv) * oHi + (long long)(z % zdiv) * oLo + oOfs;
  const int c0 = blockIdx.x * 32, r0 = blockIdx.y * 32;
  const int tx = threadIdx.x, ty = threadIdx.y;
#pragma unroll
  for (int i = 0; i < 32; i += 8)
    tile[ty + i][tx] = in[zi + (long long)(r0 + ty + i) * C + c0 + tx];
  __syncthreads();
#pragma unroll
  for (int i = 0; i < 32; i += 8)
    out[zo + (long long)(c0 + ty + i) * R + r0 + tx] = (bf16)tile[tx][ty + i];
}

// ---------------------------------------------------------------------------
// Embedding: x[row,:] = tok_emb[tok[row],:] + pos_emb[row%512,:]  (fp32)
// ---------------------------------------------------------------------------
__global__ __launch_bounds__(128) void embed_kernel(
    const int* __restrict__ tok, const float* __restrict__ temb,
    const float* __restrict__ pemb, float* __restrict__ x)
{
  const int row  = blockIdx.x;
  const int sPos = row & 511;
  const int t    = tok[row];
  const int d    = threadIdx.x * 4;
  f32x4 a = *(const f32x4*)&temb[(long long)t * 512 + d];
  f32x4 p = *(const f32x4*)&pemb[(long long)sPos * 512 + d];
  *(f32x4*)&x[(long long)row * 512 + d] = a + p;
}

// ---------------------------------------------------------------------------
// Plain LayerNorm (used after embedding only). One wave per row.
// ---------------------------------------------------------------------------
__global__ __launch_bounds__(64) void ln_kernel(
    const float* __restrict__ x, const float* __restrict__ w,
    const float* __restrict__ b, bf16* __restrict__ out)
{
  const int row = blockIdx.x;
  const int lane = threadIdx.x;
  const float* xr = x + (long long)row * 512;
  f32x4 a0 = *(const f32x4*)&xr[lane * 8];
  f32x4 a1 = *(const f32x4*)&xr[lane * 8 + 4];
  float s = 0.f, q = 0.f;
#pragma unroll
  for (int k = 0; k < 4; ++k) { s += a0[k] + a1[k]; q += a0[k]*a0[k] + a1[k]*a1[k]; }
#pragma unroll
  for (int m = 1; m < 64; m <<= 1) { s += __shfl_xor(s, m); q += __shfl_xor(q, m); }
  const float mean = s * (1.f / 512.f);
  const float var  = q * (1.f / 512.f) - mean * mean;
  const float rs   = rsqrtf(var + 1e-5f);
  f32x4 w0 = *(const f32x4*)&w[lane * 8], w1 = *(const f32x4*)&w[lane * 8 + 4];
  f32x4 b0 = *(const f32x4*)&b[lane * 8], b1 = *(const f32x4*)&b[lane * 8 + 4];
  bf16x8 o;
#pragma unroll
  for (int k = 0; k < 4; ++k) {
    o[k]     = (bf16)((a0[k] - mean) * rs * w0[k] + b0[k]);
    o[k + 4] = (bf16)((a1[k] - mean) * rs * w1[k] + b1[k]);
  }
  *(bf16x8*)&out[(long long)row * 512 + lane * 8] = o;
}

// ---------------------------------------------------------------------------
// Fused residual add + LayerNorm:  x += g + bias;  out = LN(x)*w + bb.
// 4 rows per 256-thread block (one wave per row). grid 512.
// ---------------------------------------------------------------------------
__global__ __launch_bounds__(256) void addln_kernel(
    const bf16* __restrict__ g, const float* __restrict__ bias,
    float* __restrict__ x, const float* __restrict__ w,
    const float* __restrict__ bb, bf16* __restrict__ out)
{
  const int row  = blockIdx.x * 4 + (threadIdx.x >> 6);
  const int lane = threadIdx.x & 63;
  const int c0   = lane * 8;
  float* xr = x + (long long)row * 512;
  f32x4 a0 = *(const f32x4*)&xr[c0];
  f32x4 a1 = *(const f32x4*)&xr[c0 + 4];
  bf16x8 gv = *(const bf16x8*)&g[(long long)row * 512 + c0];
  f32x4 bi0 = *(const f32x4*)&bias[c0], bi1 = *(const f32x4*)&bias[c0 + 4];
  float v[8];
#pragma unroll
  for (int k = 0; k < 4; ++k) {
    v[k]     = a0[k] + (float)gv[k]     + bi0[k];
    v[k + 4] = a1[k] + (float)gv[k + 4] + bi1[k];
  }
  *(f32x4*)&xr[c0]     = f32x4{v[0], v[1], v[2], v[3]};
  *(f32x4*)&xr[c0 + 4] = f32x4{v[4], v[5], v[6], v[7]};
  float s = 0.f, q = 0.f;
#pragma unroll
  for (int k = 0; k < 8; ++k) { s += v[k]; q += v[k] * v[k]; }
#pragma unroll
  for (int m = 1; m < 64; m <<= 1) { s += __shfl_xor(s, m); q += __shfl_xor(q, m); }
  const float mean = s * (1.f / 512.f);
  const float var  = q * (1.f / 512.f) - mean * mean;
  const float rs   = rsqrtf(var + 1e-5f);
  f32x4 w0 = *(const f32x4*)&w[c0], w1 = *(const f32x4*)&w[c0 + 4];
  f32x4 b0 = *(const f32x4*)&bb[c0], b1 = *(const f32x4*)&bb[c0 + 4];
  bf16x8 o;
#pragma unroll
  for (int k = 0; k < 4; ++k) {
    o[k]     = (bf16)((v[k] - mean) * rs * w0[k] + b0[k]);
    o[k + 4] = (bf16)((v[k + 4] - mean) * rs * w1[k] + b1[k]);
  }
  *(bf16x8*)&out[(long long)row * 512 + c0] = o;
}

// ---------------------------------------------------------------------------
// Fused flash attention. Q pre-scaled by 1/8 (folded into QKV epilogue).
// Q [(b*8+h)*512+s][64], K same layout, Vt [(b*8+h)*64+e][512].
// O [b*512+s][512] at col h*64+e (bf16).
// grid (8 q-tiles, 32 bh), block 256 (4 waves x 16 q-rows).
// MODE 0: key mask (src tok != 0); MODE 1: causal.
// ---------------------------------------------------------------------------
template <int MODE>
__global__ __launch_bounds__(256) void attn_kernel(
    const bf16* __restrict__ Q, const bf16* __restrict__ K,
    const bf16* __restrict__ Vt, bf16* __restrict__ O,
    const int* __restrict__ srctok)
{
  __shared__ bf16 Qs[64 * 72];        //  9216 B  (q rows, padded)
  __shared__ bf16 Ks[128 * 72];       // 18432 B  (key rows, padded)
  __shared__ bf16 Vs[64 * 136];       // 17408 B  (V^T: d rows, padded)
  __shared__ bf16 Ps[4 * 16 * 132];   // 16896 B  (per-wave P tiles)
  __shared__ float Ms[512];           //  2048 B  (key mask add)   total 64000

  const int bh = blockIdx.y;
  const int b  = bh >> 3;
  const int q0 = blockIdx.x * 64;
  const int tid = threadIdx.x;
  const int wv = tid >> 6, ln = tid & 63;
  const int lr = ln & 15, g = ln >> 4;
  const bf16* Qg = Q + ((long long)bh * 512 + q0) * 64;
  const bf16* Kg = K + (long long)bh * 512 * 64;
  const bf16* Vg = Vt + (long long)bh * 64 * 512;

  // stage Q tile [64][64] -> Qs[64][72]
  for (int i = tid; i < 512; i += 256) {
    const int r = i >> 3, c = (i & 7) * 8;
    *(uint4*)&Qs[r * 72 + c] = *(const uint4*)&Qg[r * 64 + c];
  }
  if (MODE == 0) {
    for (int i = tid; i < 512; i += 256)
      Ms[i] = (srctok[b * 512 + i] != 0) ? 0.f : -1e30f;
  }

  float m[4] = {-1e30f, -1e30f, -1e30f, -1e30f};
  float l[4] = {0.f, 0.f, 0.f, 0.f};
  f32x4 o[4] = {};

  const int ktEnd = (MODE == 1) ? (q0 + 64) : 512;
  bf16* Pw = Ps + wv * (16 * 132);

  for (int kt = 0; kt < ktEnd; kt += 128) {
    __syncthreads();  // prior compute done before restaging (also covers Qs/Ms 1st iter)
    // stage K tile [128][64] -> Ks[128][72]
    for (int i = tid; i < 1024; i += 256) {
      const int r = i >> 3, c = (i & 7) * 8;
      *(uint4*)&Ks[r * 72 + c] = *(const uint4*)&Kg[(long long)(kt + r) * 64 + c];
    }
    // stage V^T tile [64][128] -> Vs[64][136]
    for (int i = tid; i < 1024; i += 256) {
      const int r = i >> 4, c = (i & 15) * 8;
      *(uint4*)&Vs[r * 136 + c] = *(const uint4*)&Vg[(long long)r * 512 + kt + c];
    }
    __syncthreads();

    // S = Q_wave(16 rows) x K_tile(128)^T : frags j over keys, 2 k-steps over d
    f32x4 sf[8] = {};
#pragma unroll
    for (int s = 0; s < 2; ++s) {
      const bf16x8 aq = *(const bf16x8*)&Qs[(wv * 16 + lr) * 72 + s * 32 + g * 8];
#pragma unroll
      for (int j = 0; j < 8; ++j) {
        const bf16x8 bk = *(const bf16x8*)&Ks[(j * 16 + lr) * 72 + s * 32 + g * 8];
        sf[j] = mfma16(aq, bk, sf[j]);
      }
    }
    // mask + per-lane row max
    float rm[4] = {-1e30f, -1e30f, -1e30f, -1e30f};
#pragma unroll
    for (int j = 0; j < 8; ++j) {
      if (MODE == 0) {
        const float ma = Ms[kt + j * 16 + lr];
#pragma unroll
        for (int r = 0; r < 4; ++r) sf[j][r] += ma;
      } else {
        const int key = kt + j * 16 + lr;
#pragma unroll
        for (int r = 0; r < 4; ++r) {
          const int qq = q0 + wv * 16 + g * 4 + r;
          if (key > qq) sf[j][r] = -1e30f;
        }
      }
#pragma unroll
      for (int r = 0; r < 4; ++r) rm[r] = fmaxf(rm[r], sf[j][r]);
    }
#pragma unroll
    for (int mk = 1; mk < 16; mk <<= 1)
#pragma unroll
      for (int r = 0; r < 4; ++r) rm[r] = fmaxf(rm[r], __shfl_xor(rm[r], mk));
    float al[4], ps[4] = {0.f, 0.f, 0.f, 0.f};
#pragma unroll
    for (int r = 0; r < 4; ++r) {
      const float mx = fmaxf(m[r], rm[r]);
      al[r] = __expf(m[r] - mx);
      m[r] = mx;
    }
    // P = exp(s - m), write to LDS, accumulate row sums
#pragma unroll
    for (int j = 0; j < 8; ++j) {
#pragma unroll
      for (int r = 0; r < 4; ++r) {
        const float p = __expf(sf[j][r] - m[r]);
        ps[r] += p;
        Pw[(g * 4 + r) * 132 + j * 16 + lr] = (bf16)p;
      }
    }
#pragma unroll
    for (int mk = 1; mk < 16; mk <<= 1)
#pragma unroll
      for (int r = 0; r < 4; ++r) ps[r] += __shfl_xor(ps[r], mk);
#pragma unroll
    for (int r = 0; r < 4; ++r) l[r] = l[r] * al[r] + ps[r];
#pragma unroll
    for (int n = 0; n < 4; ++n)
#pragma unroll
      for (int r = 0; r < 4; ++r) o[n][r] *= al[r];
    // PV: O += P(16x128) x V(128x64)
#pragma unroll
    for (int ks = 0; ks < 4; ++ks) {
      const bf16x8 ap = *(const bf16x8*)&Pw[lr * 132 + ks * 32 + g * 8];
#pragma unroll
      for (int n = 0; n < 4; ++n) {
        const bf16x8 bv = *(const bf16x8*)&Vs[(n * 16 + lr) * 136 + ks * 32 + g * 8];
        o[n] = mfma16(ap, bv, o[n]);
      }
    }
  }

#pragma unroll
  for (int r = 0; r < 4; ++r) {
    const float inv = 1.f / l[r];
    const long long gr = (long long)b * 512 + q0 + wv * 16 + g * 4 + r;
#pragma unroll
    for (int n = 0; n < 4; ++n)
      O[gr * 512 + (bh & 7) * 64 + n * 16 + lr] = (bf16)(o[n][r] * inv);
  }
}

// ---------------------------------------------------------------------------
// bf16 MFMA GEMM, m97 structure. C[M,N] = A[M,K] * B^T (B given [N][K]).
// Epilogues:
//  0: C bf16 = v
//  3: C bf16 = gelu(v + bias[col])    (FFN1)
//  4: C f32  = v + bias[col]          (head logits)
//  7: qkv scatter, sel=(col>>9)+selofs(sClo): 0:q(*0.125)/1:k -> [(b8h)*512+s][64];
//     2: v -> [(b8h)*64+e][512]
// ---------------------------------------------------------------------------
template <int BM, int BN, int EPI>
__global__ __launch_bounds__(256) void gemm_kernel(
    const bf16* __restrict__ A, const bf16* __restrict__ Bw,
    void* __restrict__ Cc, const float* __restrict__ bias,
    const int K, const int lda, const int ldb, const int ldc,
    const long long sAz, const long long sBz,
    const long long sClo, const long long sChi, const int HB,
    const float scale)
{
  constexpr int BK = 64;
  __shared__ bf16 As[BM * BK];
  __shared__ bf16 Bs[BN * BK];
  constexpr int AISS = (BM * BK * 2) / 4096;
  constexpr int BISS = (BN * BK * 2) / 4096;

  const int z = blockIdx.z;
  const bf16* Az = A + (long long)z * sAz;
  const bf16* Bz = Bw + (long long)z * sBz;
  const long long cofs = (long long)(z % HB) * sClo + (long long)(z / HB) * sChi;

  const int tid  = threadIdx.x;
  const int wave = tid >> 6;
  const int lane = tid & 63;
  const int lr   = lane & 15;
  const int kg   = lane >> 4;

  const int m0 = blockIdx.x * BM;
  const int n0 = blockIdx.y * BN;

  constexpr int FM = BM / 32;
  constexpr int FN = BN / 32;
  const int wm = (wave >> 1) * (BM / 2);
  const int wn = (wave & 1) * (BN / 2);

  f32x4 acc[FM][FN] = {};

  for (int kt = 0; kt < K; kt += BK) {
#pragma unroll
    for (int i = 0; i < AISS; ++i) {
      const int o = i * 4096 + tid * 16;
      const int r = o >> 7;
      const int c = (o & 127) >> 1;
      async_copy16(Az + (long long)(m0 + r) * lda + kt + c, (bf16*)((char*)As + o));
    }
#pragma unroll
    for (int i = 0; i < BISS; ++i) {
      const int o = i * 4096 + tid * 16;
      const int r = o >> 7;
      const int c = (o & 127) >> 1;
      async_copy16(Bz + (long long)(n0 + r) * ldb + kt + c, (bf16*)((char*)Bs + o));
    }
    __syncthreads();
#pragma unroll
    for (int ks = 0; ks < 2; ++ks) {
      bf16x8 af[FM], bq[FN];
#pragma unroll
      for (int i = 0; i < FM; ++i)
        af[i] = *(const bf16x8*)&As[(wm + i * 16 + lr) * BK + ks * 32 + kg * 8];
#pragma unroll
      for (int j = 0; j < FN; ++j)
        bq[j] = *(const bf16x8*)&Bs[(wn + j * 16 + lr) * BK + ks * 32 + kg * 8];
#pragma unroll
      for (int i = 0; i < FM; ++i)
#pragma unroll
        for (int j = 0; j < FN; ++j)
          acc[i][j] = mfma16(af[i], bq[j], acc[i][j]);
    }
    __syncthreads();
  }

#pragma unroll
  for (int i = 0; i < FM; ++i) {
#pragma unroll
    for (int j = 0; j < FN; ++j) {
      const int gc = n0 + wn + j * 16 + lr;
#pragma unroll
      for (int r = 0; r < 4; ++r) {
        const int gr = m0 + wm + i * 16 + kg * 4 + r;
        const float v = acc[i][j][r];
        if constexpr (EPI == 0) {
          ((bf16*)Cc + cofs)[(long long)gr * ldc + gc] = (bf16)v;
        } else if constexpr (EPI == 3) {
          float t = v + bias[gc];
          t = 0.5f * t * (1.f + erff(t * 0.70710678118654752f));
          ((bf16*)Cc)[(long long)gr * ldc + gc] = (bf16)t;
        } else if constexpr (EPI == 4) {
          ((float*)Cc)[(long long)gr * ldc + gc] = v + bias[gc];
        } else if constexpr (EPI == 7) {
          const int sel = (gc >> 9) + (int)sClo;
          const int hh = (gc >> 6) & 7, ee = gc & 63;
          const int bb = gr >> 9, ss = gr & 511;
          bf16* base = (bf16*)Cc + (long long)sel * (2048 * 512);
          const float vv = (sel == 0) ? v * 0.125f : v;
          if (sel < 2) base[(((long long)(bb * 8 + hh) << 9) + ss) * 64 + ee] = (bf16)vv;
          else         base[(((long long)(bb * 8 + hh) << 6) + ee) * 512 + ss] = (bf16)vv;
        }
      }
    }
  }
}

// ---------------------------------------------------------------------------
// Host orchestration
// ---------------------------------------------------------------------------
extern "C" void kernel_launch(void* const* d_in, const int* in_sizes, int n_in,
                              void* d_out, int out_size, void* d_ws, size_t ws_size,
                              hipStream_t stream)
{
  const int*   tok_src   = (const int*)d_in[0];
  const int*   tok_dst   = (const int*)d_in[1];
  const float* tok_emb   = (const float*)d_in[2];
  const float* pos_emb   = (const float*)d_in[3];
  const float* enc_ln1_w = (const float*)d_in[4];
  const float* enc_ln1_b = (const float*)d_in[5];
  const float* enc_wq    = (const float*)d_in[6];
  const float* enc_wk    = (const float*)d_in[7];
  const float* enc_wv    = (const float*)d_in[8];
  const float* enc_wo    = (const float*)d_in[9];
  const float* enc_bo    = (const float*)d_in[10];
  const float* enc_ln2_w = (const float*)d_in[11];
  const float* enc_ln2_b = (const float*)d_in[12];
  const float* enc_w1    = (const float*)d_in[13];
  const float* enc_b1    = (const float*)d_in[14];
  const float* enc_w2    = (const float*)d_in[15];
  const float* enc_b2    = (const float*)d_in[16];
  const float* enc_lnf_w = (const float*)d_in[17];
  const float* enc_lnf_b = (const float*)d_in[18];
  const float* dec_ln1_w = (const float*)d_in[19];
  const float* dec_ln1_b = (const float*)d_in[20];
  const float* dec_wq_s  = (const float*)d_in[21];
  const float* dec_wk_s  = (const float*)d_in[22];
  const float* dec_wv_s  = (const float*)d_in[23];
  const float* dec_wo_s  = (const float*)d_in[24];
  const float* dec_bo_s  = (const float*)d_in[25];
  const float* dec_ln2_w = (const float*)d_in[26];
  const float* dec_ln2_b = (const float*)d_in[27];
  const float* dec_wq_c  = (const float*)d_in[28];
  const float* dec_wk_c  = (const float*)d_in[29];
  const float* dec_wv_c  = (const float*)d_in[30];
  const float* dec_wo_c  = (const float*)d_in[31];
  const float* dec_bo_c  = (const float*)d_in[32];
  const float* dec_ln3_w = (const float*)d_in[33];
  const float* dec_ln3_b = (const float*)d_in[34];
  const float* dec_w1    = (const float*)d_in[35];
  const float* dec_b1    = (const float*)d_in[36];
  const float* dec_w2    = (const float*)d_in[37];
  const float* dec_b2    = (const float*)d_in[38];
  const float* dec_lnf_w = (const float*)d_in[39];
  const float* dec_lnf_b = (const float*)d_in[40];
  const float* head_w    = (const float*)d_in[41];
  const float* head_b    = (const float*)d_in[42];
  float* outp = (float*)d_out;

  char* wp = (char*)d_ws;
  auto alloc = [&](size_t nbytes) -> char* {
    char* p = wp; wp += (nbytes + 255) & ~(size_t)255; return p;
  };
  const long long LQKV = 1536LL * 512;
  const long long LKV  = 1024LL * 512;
  const long long LSQ  = 512LL * 512;
  const long long LFF  = 2048LL * 512;

  bf16* tQKV_e = (bf16*)alloc((size_t)6 * LQKV * 2);
  bf16* tQKV_s = (bf16*)alloc((size_t)6 * LQKV * 2);
  bf16* tQ_c   = (bf16*)alloc((size_t)6 * LSQ * 2);
  bf16* tKV_c  = (bf16*)alloc((size_t)6 * LKV * 2);
  bf16* tWo_e  = (bf16*)alloc((size_t)6 * LSQ * 2);
  bf16* tWo_s  = (bf16*)alloc((size_t)6 * LSQ * 2);
  bf16* tWo_c  = (bf16*)alloc((size_t)6 * LSQ * 2);
  bf16* tW1_e  = (bf16*)alloc((size_t)6 * LFF * 2);
  bf16* tW2_e  = (bf16*)alloc((size_t)6 * LFF * 2);
  bf16* tW1_d  = (bf16*)alloc((size_t)6 * LFF * 2);
  bf16* tW2_d  = (bf16*)alloc((size_t)6 * LFF * 2);
  bf16* tHead  = (bf16*)alloc((size_t)32000 * 512 * 2);

  float* x   = (float*)alloc((size_t)2048 * 512 * 4);
  float* y   = (float*)alloc((size_t)2048 * 512 * 4);
  bf16*  h   = (bf16*)alloc((size_t)2048 * 512 * 2);
  bf16*  qkv = (bf16*)alloc((size_t)3 * 2048 * 512 * 2);
  bf16*  xe  = (bf16*)alloc((size_t)2048 * 512 * 2);
  bf16*  ob  = (bf16*)alloc((size_t)2048 * 512 * 2);
  bf16*  t0  = (bf16*)alloc((size_t)2048 * 512 * 2);
  bf16*  h1  = (bf16*)alloc((size_t)2048 * 2048 * 2);
  bf16*  yd  = (bf16*)alloc((size_t)2048 * 512 * 2);

  bf16* ql = qkv;
  bf16* kl = qkv + 2048 * 512;
  bf16* vt = qkv + 2 * 2048 * 512;

  const dim3 tb(32, 8);
  tcast_kernel<<<dim3(2, 16, 48), tb, 0, stream>>>(enc_wq, tQKV_e, 512, 64, LQKV, 32768, 8, 0);
  tcast_kernel<<<dim3(2, 16, 48), tb, 0, stream>>>(enc_wk, tQKV_e, 512, 64, LQKV, 32768, 8, 262144);
  tcast_kernel<<<dim3(2, 16, 48), tb, 0, stream>>>(enc_wv, tQKV_e, 512, 64, LQKV, 32768, 8, 524288);
  tcast_kernel<<<dim3(2, 16, 48), tb, 0, stream>>>(dec_wq_s, tQKV_s, 512, 64, LQKV, 32768, 8, 0);
  tcast_kernel<<<dim3(2, 16, 48), tb, 0, stream>>>(dec_wk_s, tQKV_s, 512, 64, LQKV, 32768, 8, 262144);
  tcast_kernel<<<dim3(2, 16, 48), tb, 0, stream>>>(dec_wv_s, tQKV_s, 512, 64, LQKV, 32768, 8, 524288);
  tcast_kernel<<<dim3(2, 16, 48), tb, 0, stream>>>(dec_wq_c, tQ_c, 512, 64, LSQ, 32768, 8, 0);
  tcast_kernel<<<dim3(2, 16, 48), tb, 0, stream>>>(dec_wk_c, tKV_c, 512, 64, LKV, 32768, 8, 0);
  tcast_kernel<<<dim3(2, 16, 48), tb, 0, stream>>>(dec_wv_c, tKV_c, 512, 64, LKV, 32768, 8, 262144);
  tcast_kernel<<<dim3(16, 16, 6), tb, 0, stream>>>(enc_wo, tWo_e, 512, 512, LSQ, 0, 1, 0);
  tcast_kernel<<<dim3(16, 16, 6), tb, 0, stream>>>(dec_wo_s, tWo_s, 512, 512, LSQ, 0, 1, 0);
  tcast_kernel<<<dim3(16, 16, 6), tb, 0, stream>>>(dec_wo_c, tWo_c, 512, 512, LSQ, 0, 1, 0);
  tcast_kernel<<<dim3(64, 16, 6), tb, 0, stream>>>(enc_w1, tW1_e, 512, 2048, LFF, 0, 1, 0);
  tcast_kernel<<<dim3(16, 64, 6), tb, 0, stream>>>(enc_w2, tW2_e, 2048, 512, LFF, 0, 1, 0);
  tcast_kernel<<<dim3(64, 16, 6), tb, 0, stream>>>(dec_w1, tW1_d, 512, 2048, LFF, 0, 1, 0);
  tcast_kernel<<<dim3(16, 64, 6), tb, 0, stream>>>(dec_w2, tW2_d, 2048, 512, LFF, 0, 1, 0);
  tcast_kernel<<<dim3(1000, 16, 1), tb, 0, stream>>>(head_w, tHead, 512, 32000, 0, 0, 1, 0);

  // ---------------- encoder ----------------
  embed_kernel<<<2048, 128, 0, stream>>>(tok_src, tok_emb, pos_emb, x);
  ln_kernel<<<2048, 64, 0, stream>>>(x, enc_ln1_w, enc_ln1_b, h);
  for (int l = 0; l < 6; ++l) {
    gemm_kernel<128, 128, 7><<<dim3(16, 12, 1), 256, 0, stream>>>(
        h, tQKV_e + (size_t)l * LQKV, qkv, nullptr, 512, 512, 512, 0, 0, 0, 0, 0, 1, 1.f);
    attn_kernel<0><<<dim3(8, 32), 256, 0, stream>>>(ql, kl, vt, ob, tok_src);
    gemm_kernel<64, 64, 0><<<dim3(32, 8, 1), 256, 0, stream>>>(
        ob, tWo_e + (size_t)l * LSQ, t0, nullptr, 512, 512, 512, 512, 0, 0, 0, 0, 1, 1.f);
    addln_kernel<<<512, 256, 0, stream>>>(t0, enc_bo + l * 512, x,
        enc_ln2_w + l * 512, enc_ln2_b + l * 512, h);
    gemm_kernel<128, 128, 3><<<dim3(16, 16, 1), 256, 0, stream>>>(
        h, tW1_e + (size_t)l * LFF, h1, enc_b1 + l * 2048, 512, 512, 512, 2048, 0, 0, 0, 0, 1, 1.f);
    gemm_kernel<64, 64, 0><<<dim3(32, 8, 1), 256, 0, stream>>>(
        h1, tW2_e + (size_t)l * LFF, t0, nullptr, 2048, 2048, 2048, 512, 0, 0, 0, 0, 1, 1.f);
    const float* nw = (l < 5) ? enc_ln1_w + (l + 1) * 512 : enc_lnf_w;
    const float* nb = (l < 5) ? enc_ln1_b + (l + 1) * 512 : enc_lnf_b;
    addln_kernel<<<512, 256, 0, stream>>>(t0, enc_b2 + l * 512, x, nw, nb, (l < 5) ? h : xe);
  }

  // ---------------- decoder ----------------
  embed_kernel<<<2048, 128, 0, stream>>>(tok_dst, tok_emb, pos_emb, y);
  ln_kernel<<<2048, 64, 0, stream>>>(y, dec_ln1_w, dec_ln1_b, h);
  for (int l = 0; l < 6; ++l) {
    // self-attention (causal)
    gemm_kernel<128, 128, 7><<<dim3(16, 12, 1), 256, 0, stream>>>(
        h, tQKV_s + (size_t)l * LQKV, qkv, nullptr, 512, 512, 512, 0, 0, 0, 0, 0, 1, 1.f);
    attn_kernel<1><<<dim3(8, 32), 256, 0, stream>>>(ql, kl, vt, ob, nullptr);
    gemm_kernel<64, 64, 0><<<dim3(32, 8, 1), 256, 0, stream>>>(
        ob, tWo_s + (size_t)l * LSQ, t0, nullptr, 512, 512, 512, 512, 0, 0, 0, 0, 1, 1.f);
    addln_kernel<<<512, 256, 0, stream>>>(t0, dec_bo_s + l * 512, y,
        dec_ln2_w + l * 512, dec_ln2_b + l * 512, h);
    // cross-attention
    gemm_kernel<64, 64, 7><<<dim3(32, 8, 1), 256, 0, stream>>>(
        h, tQ_c + (size_t)l * LSQ, qkv, nullptr, 512, 512, 512, 0, 0, 0, 0, 0, 1, 1.f);
    gemm_kernel<128, 128, 7><<<dim3(16, 8, 1), 256, 0, stream>>>(
        xe, tKV_c + (size_t)l * LKV, qkv, nullptr, 512, 512, 512, 0, 0, 0, 1, 0, 1, 1.f);
    attn_kernel<0><<<dim3(8, 32), 256, 0, stream>>>(ql, kl, vt, ob, tok_src);
    gemm_kernel<64, 64, 0><<<dim3(32, 8, 1), 256, 0, stream>>>(
        ob, tWo_c + (size_t)l * LSQ, t0, nullptr, 512, 512, 512, 512, 0, 0, 0, 0, 1, 1.f);
    addln_kernel<<<512, 256, 0, stream>>>(t0, dec_bo_c + l * 512, y,
        dec_ln3_w + l * 512, dec_ln3_b + l * 512, h);
    // FFN
    gemm_kernel<128, 128, 3><<<dim3(16, 16, 1), 256, 0, stream>>>(
        h, tW1_d + (size_t)l * LFF, h1, dec_b1 + l * 2048, 512, 512, 512, 2048, 0, 0, 0, 0, 1, 1.f);
    gemm_kernel<64, 64, 0><<<dim3(32, 8, 1), 256, 0, stream>>>(
        h1, tW2_d + (size_t)l * LFF, t0, nullptr, 2048, 2048, 2048, 512, 0, 0, 0, 0, 1, 1.f);
    const float* nw = (l < 5) ? dec_ln1_w + (l + 1) * 512 : dec_lnf_w;
    const float* nb = (l < 5) ? dec_ln1_b + (l + 1) * 512 : dec_lnf_b;
    addln_kernel<<<512, 256, 0, stream>>>(t0, dec_b2 + l * 512, y, nw, nb, (l < 5) ? h : yd);
  }
  // head: logits [2048, 32000] fp32
  gemm_kernel<128, 128, 4><<<dim3(16, 250, 1), 256, 0, stream>>>(
      yd, tHead, outp, head_b, 512, 512, 512, 32000, 0, 0, 0, 0, 1, 1.f);
}

// Round 4
// 2251.888 us; speedup vs baseline: 1.5764x; 1.0507x over previous
//
#include <hip/hip_runtime.h>
#include <math.h>

// ---------------------------------------------------------------------------
// SimpleTranslate encoder-decoder forward, MI355X/gfx950.
// Round 3: attn reads K/V direct from L2 (no LDS staging, 1-wave blocks),
// cross-KV hoisted+batched, single fused weight-repack launch, head GEMM
// XCD-swizzled + nontemporal stores.
// ---------------------------------------------------------------------------

typedef __bf16 bf16;
typedef bf16  bf16x8 __attribute__((ext_vector_type(8)));
typedef float f32x4  __attribute__((ext_vector_type(4)));

#define DEV __device__ __forceinline__

DEV f32x4 mfma16(bf16x8 a, bf16x8 b, f32x4 c) {
  return __builtin_amdgcn_mfma_f32_16x16x32_bf16(a, b, c, 0, 0, 0);
}

DEV void async_copy16(const bf16* g, bf16* l) {
  __builtin_amdgcn_global_load_lds(
      (__attribute__((address_space(1))) void*)(g),
      (__attribute__((address_space(3))) void*)(l), 16, 0, 0);
}

// ---------------------------------------------------------------------------
// Fused weight repack: transpose + fp32->bf16 for all weight arrays, one
// launch. Each 32x32 tile indexed by a job table.
// ---------------------------------------------------------------------------
struct TJob { const float* in; bf16* out; long long oHi, oLo, oOfs; int R, C, zdiv, tile0; };
struct TJobs { TJob j[17]; };

__global__ __launch_bounds__(256) void tcast_all(TJobs JJ, int njobs)
{
  __shared__ float tile[32][33];
  const int t = blockIdx.x;
  int ji = 0;
#pragma unroll
  for (int k = 1; k < 17; ++k) if (k < njobs && JJ.j[k].tile0 <= t) ji = k;
  const TJob J = JJ.j[ji];
  const int rel  = t - J.tile0;
  const int ntx  = J.C >> 5, nty = J.R >> 5;
  const int perz = ntx * nty;
  const int z    = rel / perz;
  const int r2   = rel - z * perz;
  const int bx   = r2 % ntx, by = r2 / ntx;

  const long long zi = (long long)z * J.R * J.C;
  const long long zo = (long long)(z / J.zdiv) * J.oHi + (long long)(z % J.zdiv) * J.oLo + J.oOfs;
  const int c0 = bx * 32, r0 = by * 32;
  const int tx = threadIdx.x & 31, ty = (threadIdx.x >> 5);
#pragma unroll
  for (int i = 0; i < 32; i += 8)
    tile[ty + i][tx] = J.in[zi + (long long)(r0 + ty + i) * J.C + c0 + tx];
  __syncthreads();
#pragma unroll
  for (int i = 0; i < 32; i += 8)
    J.out[zo + (long long)(c0 + ty + i) * J.R + r0 + tx] = (bf16)tile[tx][ty + i];
}

// ---------------------------------------------------------------------------
// Fused embedding + LayerNorm: x = temb[tok]+pemb (fp32 saved), h = LN(x).
// One wave per row, grid 2048.
// ---------------------------------------------------------------------------
__global__ __launch_bounds__(64) void embedln_kernel(
    const int* __restrict__ tok, const float* __restrict__ temb,
    const float* __restrict__ pemb, float* __restrict__ x,
    const float* __restrict__ w, const float* __restrict__ b,
    bf16* __restrict__ out)
{
  const int row  = blockIdx.x;
  const int sPos = row & 511;
  const int t    = tok[row];
  const int lane = threadIdx.x;
  const int c0   = lane * 8;
  f32x4 a0 = *(const f32x4*)&temb[(long long)t * 512 + c0];
  f32x4 a1 = *(const f32x4*)&temb[(long long)t * 512 + c0 + 4];
  f32x4 p0 = *(const f32x4*)&pemb[(long long)sPos * 512 + c0];
  f32x4 p1 = *(const f32x4*)&pemb[(long long)sPos * 512 + c0 + 4];
  a0 += p0; a1 += p1;
  *(f32x4*)&x[(long long)row * 512 + c0]     = a0;
  *(f32x4*)&x[(long long)row * 512 + c0 + 4] = a1;
  float s = 0.f, q = 0.f;
#pragma unroll
  for (int k = 0; k < 4; ++k) { s += a0[k] + a1[k]; q += a0[k]*a0[k] + a1[k]*a1[k]; }
#pragma unroll
  for (int m = 1; m < 64; m <<= 1) { s += __shfl_xor(s, m); q += __shfl_xor(q, m); }
  const float mean = s * (1.f / 512.f);
  const float var  = q * (1.f / 512.f) - mean * mean;
  const float rs   = rsqrtf(var + 1e-5f);
  f32x4 w0 = *(const f32x4*)&w[c0], w1 = *(const f32x4*)&w[c0 + 4];
  f32x4 b0 = *(const f32x4*)&b[c0], b1 = *(const f32x4*)&b[c0 + 4];
  bf16x8 o;
#pragma unroll
  for (int k = 0; k < 4; ++k) {
    o[k]     = (bf16)((a0[k] - mean) * rs * w0[k] + b0[k]);
    o[k + 4] = (bf16)((a1[k] - mean) * rs * w1[k] + b1[k]);
  }
  *(bf16x8*)&out[(long long)row * 512 + c0] = o;
}

// ---------------------------------------------------------------------------
// Fused residual add + LayerNorm:  x += g + bias;  out = LN(x)*w + bb.
// ---------------------------------------------------------------------------
__global__ __launch_bounds__(256) void addln_kernel(
    const bf16* __restrict__ g, const float* __restrict__ bias,
    float* __restrict__ x, const float* __restrict__ w,
    const float* __restrict__ bb, bf16* __restrict__ out)
{
  const int row  = blockIdx.x * 4 + (threadIdx.x >> 6);
  const int lane = threadIdx.x & 63;
  const int c0   = lane * 8;
  float* xr = x + (long long)row * 512;
  f32x4 a0 = *(const f32x4*)&xr[c0];
  f32x4 a1 = *(const f32x4*)&xr[c0 + 4];
  bf16x8 gv = *(const bf16x8*)&g[(long long)row * 512 + c0];
  f32x4 bi0 = *(const f32x4*)&bias[c0], bi1 = *(const f32x4*)&bias[c0 + 4];
  float v[8];
#pragma unroll
  for (int k = 0; k < 4; ++k) {
    v[k]     = a0[k] + (float)gv[k]     + bi0[k];
    v[k + 4] = a1[k] + (float)gv[k + 4] + bi1[k];
  }
  *(f32x4*)&xr[c0]     = f32x4{v[0], v[1], v[2], v[3]};
  *(f32x4*)&xr[c0 + 4] = f32x4{v[4], v[5], v[6], v[7]};
  float s = 0.f, q = 0.f;
#pragma unroll
  for (int k = 0; k < 8; ++k) { s += v[k]; q += v[k] * v[k]; }
#pragma unroll
  for (int m = 1; m < 64; m <<= 1) { s += __shfl_xor(s, m); q += __shfl_xor(q, m); }
  const float mean = s * (1.f / 512.f);
  const float var  = q * (1.f / 512.f) - mean * mean;
  const float rs   = rsqrtf(var + 1e-5f);
  f32x4 w0 = *(const f32x4*)&w[c0], w1 = *(const f32x4*)&w[c0 + 4];
  f32x4 b0 = *(const f32x4*)&bb[c0], b1 = *(const f32x4*)&bb[c0 + 4];
  bf16x8 o;
#pragma unroll
  for (int k = 0; k < 4; ++k) {
    o[k]     = (bf16)((v[k] - mean) * rs * w0[k] + b0[k]);
    o[k + 4] = (bf16)((v[k + 4] - mean) * rs * w1[k] + b1[k]);
  }
  *(bf16x8*)&out[(long long)row * 512 + c0] = o;
}

// ---------------------------------------------------------------------------
// Flash attention v3: 1 wave per block, 16 q-rows; K/V read direct from
// global (L2-resident: 128 KB per head). No __syncthreads at all.
// Q pre-scaled by 1/8. Q/K [(b*8+h)*512+s][64], Vt [(b*8+h)*64+e][512].
// O [b*512+s][512] at col h*64+e. grid (32 q-tiles, 32 bh), block 64.
// MODE 0: key mask (src tok != 0); MODE 1: causal.
// ---------------------------------------------------------------------------
template <int MODE>
__global__ __launch_bounds__(64) void attn_kernel(
    const bf16* __restrict__ Q, const bf16* __restrict__ K,
    const bf16* __restrict__ Vt, bf16* __restrict__ O,
    const int* __restrict__ srctok)
{
  __shared__ bf16 Pw[16 * 68];
  const int bh = blockIdx.y;
  const int b  = bh >> 3;
  const int q0 = blockIdx.x * 16;
  const int ln = threadIdx.x;
  const int lr = ln & 15, g = ln >> 4;
  const bf16* Qg = Q + ((long long)bh * 512 + q0) * 64;
  const bf16* Kg = K + (long long)bh * 512 * 64;
  const bf16* Vg = Vt + (long long)bh * 64 * 512;
  const int* tkb = srctok + b * 512;

  const bf16x8 aq0 = *(const bf16x8*)&Qg[lr * 64 + g * 8];
  const bf16x8 aq1 = *(const bf16x8*)&Qg[lr * 64 + 32 + g * 8];

  float m[4] = {-1e30f, -1e30f, -1e30f, -1e30f};
  float l[4] = {0.f, 0.f, 0.f, 0.f};
  f32x4 o[4] = {};

  const int ktEnd = (MODE == 1) ? (q0 + 16) : 512;
  for (int kt = 0; kt < ktEnd; kt += 64) {
    // S = Q(16) x K_tile(64)^T
    f32x4 sf[4] = {};
#pragma unroll
    for (int j = 0; j < 4; ++j) {
      const bf16x8 bk0 = *(const bf16x8*)&Kg[(long long)(kt + j * 16 + lr) * 64 + g * 8];
      const bf16x8 bk1 = *(const bf16x8*)&Kg[(long long)(kt + j * 16 + lr) * 64 + 32 + g * 8];
      sf[j] = mfma16(aq0, bk0, sf[j]);
      sf[j] = mfma16(aq1, bk1, sf[j]);
    }
    // mask + row max
    float rm[4] = {-1e30f, -1e30f, -1e30f, -1e30f};
#pragma unroll
    for (int j = 0; j < 4; ++j) {
      if (MODE == 0) {
        const bool ok = (tkb[kt + j * 16 + lr] != 0);
#pragma unroll
        for (int r = 0; r < 4; ++r) if (!ok) sf[j][r] = -1e30f;
      } else {
        const int key = kt + j * 16 + lr;
#pragma unroll
        for (int r = 0; r < 4; ++r)
          if (key > q0 + g * 4 + r) sf[j][r] = -1e30f;
      }
#pragma unroll
      for (int r = 0; r < 4; ++r) rm[r] = fmaxf(rm[r], sf[j][r]);
    }
#pragma unroll
    for (int mk = 1; mk < 16; mk <<= 1)
#pragma unroll
      for (int r = 0; r < 4; ++r) rm[r] = fmaxf(rm[r], __shfl_xor(rm[r], mk));
    float al[4], ps[4] = {0.f, 0.f, 0.f, 0.f};
#pragma unroll
    for (int r = 0; r < 4; ++r) {
      const float mx = fmaxf(m[r], rm[r]);
      al[r] = __expf(m[r] - mx);
      m[r] = mx;
    }
    // P = exp(s - m) (0 when masked), to LDS; accumulate row sums
#pragma unroll
    for (int j = 0; j < 4; ++j) {
#pragma unroll
      for (int r = 0; r < 4; ++r) {
        const float p = (sf[j][r] <= -1e29f) ? 0.f : __expf(sf[j][r] - m[r]);
        ps[r] += p;
        Pw[(g * 4 + r) * 68 + j * 16 + lr] = (bf16)p;
      }
    }
#pragma unroll
    for (int mk = 1; mk < 16; mk <<= 1)
#pragma unroll
      for (int r = 0; r < 4; ++r) ps[r] += __shfl_xor(ps[r], mk);
#pragma unroll
    for (int r = 0; r < 4; ++r) l[r] = l[r] * al[r] + ps[r];
#pragma unroll
    for (int n = 0; n < 4; ++n)
#pragma unroll
      for (int r = 0; r < 4; ++r) o[n][r] *= al[r];
    // PV: O(16x64) += P(16x64) x V(64x64), V frags direct from global
#pragma unroll
    for (int ks = 0; ks < 2; ++ks) {
      const bf16x8 ap = *(const bf16x8*)&Pw[lr * 68 + ks * 32 + g * 8];
#pragma unroll
      for (int n = 0; n < 4; ++n) {
        const bf16x8 bv = *(const bf16x8*)&Vg[(long long)(n * 16 + lr) * 512 + kt + ks * 32 + g * 8];
        o[n] = mfma16(ap, bv, o[n]);
      }
    }
  }

#pragma unroll
  for (int r = 0; r < 4; ++r) {
    const float inv = 1.f / l[r];
    const long long gr = (long long)b * 512 + q0 + g * 4 + r;
#pragma unroll
    for (int n = 0; n < 4; ++n)
      O[gr * 512 + (bh & 7) * 64 + n * 16 + lr] = (bf16)(o[n][r] * inv);
  }
}

// ---------------------------------------------------------------------------
// bf16 MFMA GEMM, m97 structure. C[M,N] = A[M,K] * B^T (B given [N][K]).
// Epilogues:
//  0: C bf16 = v
//  3: C bf16 = gelu(v + bias[col])    (FFN1)
//  4: C f32  = v + bias[col] (nontemporal; head logits)
//  7: qkv scatter, sel=gc>>9: 0:q(*0.125)/1:k -> [(b8h)*512+s][64]; 2: v^T
//  8: per-z cross-KV scatter: base = Cc + z*sChi; sel=gc>>9: 0:k / 1:v^T
// SWZ: bijective XCD swizzle over flattened grid (requires nwg%8==0).
// ---------------------------------------------------------------------------
template <int BM, int BN, int EPI, bool SWZ = false>
__global__ __launch_bounds__(256) void gemm_kernel(
    const bf16* __restrict__ A, const bf16* __restrict__ Bw,
    void* __restrict__ Cc, const float* __restrict__ bias,
    const int K, const int lda, const int ldb, const int ldc,
    const long long sAz, const long long sBz,
    const long long sClo, const long long sChi, const int HB,
    const float scale)
{
  constexpr int BK = 64;
  __shared__ bf16 As[BM * BK];
  __shared__ bf16 Bs[BN * BK];
  constexpr int AISS = (BM * BK * 2) / 4096;
  constexpr int BISS = (BN * BK * 2) / 4096;

  const int z = blockIdx.z;
  const bf16* Az = A + (long long)z * sAz;
  const bf16* Bz = Bw + (long long)z * sBz;
  const long long cofs = (long long)(z % HB) * sClo + (long long)(z / HB) * sChi;

  const int tid  = threadIdx.x;
  const int wave = tid >> 6;
  const int lane = tid & 63;
  const int lr   = lane & 15;
  const int kg   = lane >> 4;

  int bx = blockIdx.x, by = blockIdx.y;
  if constexpr (SWZ) {
    const int nx = gridDim.x;
    const int nwg = nx * gridDim.y;
    const int id = by * nx + bx;
    const int chunk = nwg >> 3;
    const int swz = (id & 7) * chunk + (id >> 3);
    bx = swz % nx; by = swz / nx;
  }
  const int m0 = bx * BM;
  const int n0 = by * BN;

  constexpr int FM = BM / 32;
  constexpr int FN = BN / 32;
  const int wm = (wave >> 1) * (BM / 2);
  const int wn = (wave & 1) * (BN / 2);

  f32x4 acc[FM][FN] = {};

  for (int kt = 0; kt < K; kt += BK) {
#pragma unroll
    for (int i = 0; i < AISS; ++i) {
      const int o = i * 4096 + tid * 16;
      const int r = o >> 7;
      const int c = (o & 127) >> 1;
      async_copy16(Az + (long long)(m0 + r) * lda + kt + c, (bf16*)((char*)As + o));
    }
#pragma unroll
    for (int i = 0; i < BISS; ++i) {
      const int o = i * 4096 + tid * 16;
      const int r = o >> 7;
      const int c = (o & 127) >> 1;
      async_copy16(Bz + (long long)(n0 + r) * ldb + kt + c, (bf16*)((char*)Bs + o));
    }
    __syncthreads();
#pragma unroll
    for (int ks = 0; ks < 2; ++ks) {
      bf16x8 af[FM], bq[FN];
#pragma unroll
      for (int i = 0; i < FM; ++i)
        af[i] = *(const bf16x8*)&As[(wm + i * 16 + lr) * BK + ks * 32 + kg * 8];
#pragma unroll
      for (int j = 0; j < FN; ++j)
        bq[j] = *(const bf16x8*)&Bs[(wn + j * 16 + lr) * BK + ks * 32 + kg * 8];
#pragma unroll
      for (int i = 0; i < FM; ++i)
#pragma unroll
        for (int j = 0; j < FN; ++j)
          acc[i][j] = mfma16(af[i], bq[j], acc[i][j]);
    }
    __syncthreads();
  }

#pragma unroll
  for (int i = 0; i < FM; ++i) {
#pragma unroll
    for (int j = 0; j < FN; ++j) {
      const int gc = n0 + wn + j * 16 + lr;
#pragma unroll
      for (int r = 0; r < 4; ++r) {
        const int gr = m0 + wm + i * 16 + kg * 4 + r;
        const float v = acc[i][j][r];
        if constexpr (EPI == 0) {
          ((bf16*)Cc + cofs)[(long long)gr * ldc + gc] = (bf16)v;
        } else if constexpr (EPI == 3) {
          float t = v + bias[gc];
          t = 0.5f * t * (1.f + erff(t * 0.70710678118654752f));
          ((bf16*)Cc)[(long long)gr * ldc + gc] = (bf16)t;
        } else if constexpr (EPI == 4) {
          __builtin_nontemporal_store(v + bias[gc], &((float*)Cc)[(long long)gr * ldc + gc]);
        } else if constexpr (EPI == 7) {
          const int sel = gc >> 9;
          const int hh = (gc >> 6) & 7, ee = gc & 63;
          const int bb = gr >> 9, ss = gr & 511;
          bf16* base = (bf16*)Cc + (long long)sel * (2048 * 512);
          const float vv = (sel == 0) ? v * 0.125f : v;
          if (sel < 2) base[(((long long)(bb * 8 + hh) << 9) + ss) * 64 + ee] = (bf16)vv;
          else         base[(((long long)(bb * 8 + hh) << 6) + ee) * 512 + ss] = (bf16)vv;
        } else if constexpr (EPI == 8) {
          const int sel = gc >> 9;
          const int hh = (gc >> 6) & 7, ee = gc & 63;
          const int bb = gr >> 9, ss = gr & 511;
          bf16* base = (bf16*)Cc + (long long)z * sChi + (long long)sel * (2048 * 512);
          if (sel == 0) base[(((long long)(bb * 8 + hh) << 9) + ss) * 64 + ee] = (bf16)v;
          else          base[(((long long)(bb * 8 + hh) << 6) + ee) * 512 + ss] = (bf16)v;
        }
      }
    }
  }
}

// ---------------------------------------------------------------------------
// Host orchestration
// ---------------------------------------------------------------------------
extern "C" void kernel_launch(void* const* d_in, const int* in_sizes, int n_in,
                              void* d_out, int out_size, void* d_ws, size_t ws_size,
                              hipStream_t stream)
{
  const int*   tok_src   = (const int*)d_in[0];
  const int*   tok_dst   = (const int*)d_in[1];
  const float* tok_emb   = (const float*)d_in[2];
  const float* pos_emb   = (const float*)d_in[3];
  const float* enc_ln1_w = (const float*)d_in[4];
  const float* enc_ln1_b = (const float*)d_in[5];
  const float* enc_wq    = (const float*)d_in[6];
  const float* enc_wk    = (const float*)d_in[7];
  const float* enc_wv    = (const float*)d_in[8];
  const float* enc_wo    = (const float*)d_in[9];
  const float* enc_bo    = (const float*)d_in[10];
  const float* enc_ln2_w = (const float*)d_in[11];
  const float* enc_ln2_b = (const float*)d_in[12];
  const float* enc_w1    = (const float*)d_in[13];
  const float* enc_b1    = (const float*)d_in[14];
  const float* enc_w2    = (const float*)d_in[15];
  const float* enc_b2    = (const float*)d_in[16];
  const float* enc_lnf_w = (const float*)d_in[17];
  const float* enc_lnf_b = (const float*)d_in[18];
  const float* dec_ln1_w = (const float*)d_in[19];
  const float* dec_ln1_b = (const float*)d_in[20];
  const float* dec_wq_s  = (const float*)d_in[21];
  const float* dec_wk_s  = (const float*)d_in[22];
  const float* dec_wv_s  = (const float*)d_in[23];
  const float* dec_wo_s  = (const float*)d_in[24];
  const float* dec_bo_s  = (const float*)d_in[25];
  const float* dec_ln2_w = (const float*)d_in[26];
  const float* dec_ln2_b = (const float*)d_in[27];
  const float* dec_wq_c  = (const float*)d_in[28];
  const float* dec_wk_c  = (const float*)d_in[29];
  const float* dec_wv_c  = (const float*)d_in[30];
  const float* dec_wo_c  = (const float*)d_in[31];
  const float* dec_bo_c  = (const float*)d_in[32];
  const float* dec_ln3_w = (const float*)d_in[33];
  const float* dec_ln3_b = (const float*)d_in[34];
  const float* dec_w1    = (const float*)d_in[35];
  const float* dec_b1    = (const float*)d_in[36];
  const float* dec_w2    = (const float*)d_in[37];
  const float* dec_b2    = (const float*)d_in[38];
  const float* dec_lnf_w = (const float*)d_in[39];
  const float* dec_lnf_b = (const float*)d_in[40];
  const float* head_w    = (const float*)d_in[41];
  const float* head_b    = (const float*)d_in[42];
  float* outp = (float*)d_out;

  char* wp = (char*)d_ws;
  auto alloc = [&](size_t nbytes) -> char* {
    char* p = wp; wp += (nbytes + 255) & ~(size_t)255; return p;
  };
  const long long LQKV = 1536LL * 512;
  const long long LKV  = 1024LL * 512;
  const long long LSQ  = 512LL * 512;
  const long long LFF  = 2048LL * 512;
  const long long KVST = 2LL * 2048 * 512;   // per-layer cross K+V^T elements

  bf16* tQKV_e = (bf16*)alloc((size_t)6 * LQKV * 2);
  bf16* tQKV_s = (bf16*)alloc((size_t)6 * LQKV * 2);
  bf16* tQ_c   = (bf16*)alloc((size_t)6 * LSQ * 2);
  bf16* tKV_c  = (bf16*)alloc((size_t)6 * LKV * 2);
  bf16* tWo_e  = (bf16*)alloc((size_t)6 * LSQ * 2);
  bf16* tWo_s  = (bf16*)alloc((size_t)6 * LSQ * 2);
  bf16* tWo_c  = (bf16*)alloc((size_t)6 * LSQ * 2);
  bf16* tW1_e  = (bf16*)alloc((size_t)6 * LFF * 2);
  bf16* tW2_e  = (bf16*)alloc((size_t)6 * LFF * 2);
  bf16* tW1_d  = (bf16*)alloc((size_t)6 * LFF * 2);
  bf16* tW2_d  = (bf16*)alloc((size_t)6 * LFF * 2);
  bf16* tHead  = (bf16*)alloc((size_t)32000 * 512 * 2);

  float* x   = (float*)alloc((size_t)2048 * 512 * 4);
  float* y   = (float*)alloc((size_t)2048 * 512 * 4);
  bf16*  h   = (bf16*)alloc((size_t)2048 * 512 * 2);
  bf16*  qkv = (bf16*)alloc((size_t)3 * 2048 * 512 * 2);
  bf16*  xe  = (bf16*)alloc((size_t)2048 * 512 * 2);
  bf16*  kvc = (bf16*)alloc((size_t)6 * KVST * 2);   // all-layer cross K/V
  bf16*  ob  = (bf16*)alloc((size_t)2048 * 512 * 2);
  bf16*  t0  = (bf16*)alloc((size_t)2048 * 512 * 2);
  bf16*  h1  = (bf16*)alloc((size_t)2048 * 2048 * 2);
  bf16*  yd  = (bf16*)alloc((size_t)2048 * 512 * 2);

  bf16* ql = qkv;
  bf16* kl = qkv + 2048 * 512;
  bf16* vt = qkv + 2 * 2048 * 512;

  // --- single fused weight repack ---
  TJobs JJ; int nt = 0, nj = 0;
  auto addjob = [&](const float* in, bf16* out, int R, int C,
                    long long oHi, long long oLo, int zdiv, long long oOfs, int nz) {
    JJ.j[nj] = TJob{in, out, oHi, oLo, oOfs, R, C, zdiv, nt};
    nt += (C / 32) * (R / 32) * nz; ++nj;
  };
  addjob(enc_wq,   tQKV_e, 512, 64,   LQKV, 32768, 8, 0,      48);
  addjob(enc_wk,   tQKV_e, 512, 64,   LQKV, 32768, 8, 262144, 48);
  addjob(enc_wv,   tQKV_e, 512, 64,   LQKV, 32768, 8, 524288, 48);
  addjob(dec_wq_s, tQKV_s, 512, 64,   LQKV, 32768, 8, 0,      48);
  addjob(dec_wk_s, tQKV_s, 512, 64,   LQKV, 32768, 8, 262144, 48);
  addjob(dec_wv_s, tQKV_s, 512, 64,   LQKV, 32768, 8, 524288, 48);
  addjob(dec_wq_c, tQ_c,   512, 64,   LSQ,  32768, 8, 0,      48);
  addjob(dec_wk_c, tKV_c,  512, 64,   LKV,  32768, 8, 0,      48);
  addjob(dec_wv_c, tKV_c,  512, 64,   LKV,  32768, 8, 262144, 48);
  addjob(enc_wo,   tWo_e,  512, 512,  LSQ,  0, 1, 0, 6);
  addjob(dec_wo_s, tWo_s,  512, 512,  LSQ,  0, 1, 0, 6);
  addjob(dec_wo_c, tWo_c,  512, 512,  LSQ,  0, 1, 0, 6);
  addjob(enc_w1,   tW1_e,  512, 2048, LFF,  0, 1, 0, 6);
  addjob(enc_w2,   tW2_e,  2048, 512, LFF,  0, 1, 0, 6);
  addjob(dec_w1,   tW1_d,  512, 2048, LFF,  0, 1, 0, 6);
  addjob(dec_w2,   tW2_d,  2048, 512, LFF,  0, 1, 0, 6);
  addjob(head_w,   tHead,  512, 32000, 0,   0, 1, 0, 1);
  tcast_all<<<nt, 256, 0, stream>>>(JJ, nj);

  // ---------------- encoder ----------------
  embedln_kernel<<<2048, 64, 0, stream>>>(tok_src, tok_emb, pos_emb, x, enc_ln1_w, enc_ln1_b, h);
  for (int l = 0; l < 6; ++l) {
    gemm_kernel<128, 128, 7><<<dim3(16, 12, 1), 256, 0, stream>>>(
        h, tQKV_e + (size_t)l * LQKV, qkv, nullptr, 512, 512, 512, 0, 0, 0, 0, 0, 1, 1.f);
    attn_kernel<0><<<dim3(32, 32), 64, 0, stream>>>(ql, kl, vt, ob, tok_src);
    gemm_kernel<64, 64, 0><<<dim3(32, 8, 1), 256, 0, stream>>>(
        ob, tWo_e + (size_t)l * LSQ, t0, nullptr, 512, 512, 512, 512, 0, 0, 0, 0, 1, 1.f);
    addln_kernel<<<512, 256, 0, stream>>>(t0, enc_bo + l * 512, x,
        enc_ln2_w + l * 512, enc_ln2_b + l * 512, h);
    gemm_kernel<128, 128, 3><<<dim3(16, 16, 1), 256, 0, stream>>>(
        h, tW1_e + (size_t)l * LFF, h1, enc_b1 + l * 2048, 512, 512, 512, 2048, 0, 0, 0, 0, 1, 1.f);
    gemm_kernel<64, 64, 0><<<dim3(32, 8, 1), 256, 0, stream>>>(
        h1, tW2_e + (size_t)l * LFF, t0, nullptr, 2048, 2048, 2048, 512, 0, 0, 0, 0, 1, 1.f);
    const float* nw = (l < 5) ? enc_ln1_w + (l + 1) * 512 : enc_lnf_w;
    const float* nb = (l < 5) ? enc_ln1_b + (l + 1) * 512 : enc_lnf_b;
    addln_kernel<<<512, 256, 0, stream>>>(t0, enc_b2 + l * 512, x, nw, nb, (l < 5) ? h : xe);
  }

  // all-layer cross K/V from xe (z = layer)
  gemm_kernel<128, 128, 8><<<dim3(16, 8, 6), 256, 0, stream>>>(
      xe, tKV_c, kvc, nullptr, 512, 512, 512, 0, 0, LKV, 0, KVST, 1, 1.f);

  // ---------------- decoder ----------------
  embedln_kernel<<<2048, 64, 0, stream>>>(tok_dst, tok_emb, pos_emb, y, dec_ln1_w, dec_ln1_b, h);
  for (int l = 0; l < 6; ++l) {
    // self-attention (causal)
    gemm_kernel<128, 128, 7><<<dim3(16, 12, 1), 256, 0, stream>>>(
        h, tQKV_s + (size_t)l * LQKV, qkv, nullptr, 512, 512, 512, 0, 0, 0, 0, 0, 1, 1.f);
    attn_kernel<1><<<dim3(32, 32), 64, 0, stream>>>(ql, kl, vt, ob, nullptr);
    gemm_kernel<64, 64, 0><<<dim3(32, 8, 1), 256, 0, stream>>>(
        ob, tWo_s + (size_t)l * LSQ, t0, nullptr, 512, 512, 512, 512, 0, 0, 0, 0, 1, 1.f);
    addln_kernel<<<512, 256, 0, stream>>>(t0, dec_bo_s + l * 512, y,
        dec_ln2_w + l * 512, dec_ln2_b + l * 512, h);
    // cross-attention (K/V precomputed in kvc)
    gemm_kernel<64, 64, 7><<<dim3(32, 8, 1), 256, 0, stream>>>(
        h, tQ_c + (size_t)l * LSQ, qkv, nullptr, 512, 512, 512, 0, 0, 0, 0, 0, 1, 1.f);
    attn_kernel<0><<<dim3(32, 32), 64, 0, stream>>>(
        ql, kvc + (size_t)l * KVST, kvc + (size_t)l * KVST + 2048 * 512, ob, tok_src);
    gemm_kernel<64, 64, 0><<<dim3(32, 8, 1), 256, 0, stream>>>(
        ob, tWo_c + (size_t)l * LSQ, t0, nullptr, 512, 512, 512, 512, 0, 0, 0, 0, 1, 1.f);
    addln_kernel<<<512, 256, 0, stream>>>(t0, dec_bo_c + l * 512, y,
        dec_ln3_w + l * 512, dec_ln3_b + l * 512, h);
    // FFN
    gemm_kernel<128, 128, 3><<<dim3(16, 16, 1), 256, 0, stream>>>(
        h, tW1_d + (size_t)l * LFF, h1, dec_b1 + l * 2048, 512, 512, 512, 2048, 0, 0, 0, 0, 1, 1.f);
    gemm_kernel<64, 64, 0><<<dim3(32, 8, 1), 256, 0, stream>>>(
        h1, tW2_d + (size_t)l * LFF, t0, nullptr, 2048, 2048, 2048, 512, 0, 0, 0, 0, 1, 1.f);
    const float* nw = (l < 5) ? dec_ln1_w + (l + 1) * 512 : dec_lnf_w;
    const float* nb = (l < 5) ? dec_ln1_b + (l + 1) * 512 : dec_lnf_b;
    addln_kernel<<<512, 256, 0, stream>>>(t0, dec_b2 + l * 512, y, nw, nb, (l < 5) ? h : yd);
  }
  // head: logits [2048, 32000] fp32, XCD-swizzled, nontemporal stores
  gemm_kernel<128, 128, 4, true><<<dim3(16, 250, 1), 256, 0, stream>>>(
      yd, tHead, outp, head_b, 512, 512, 512, 32000, 0, 0, 0, 0, 1, 1.f);
}

// Round 5
// 2143.703 us; speedup vs baseline: 1.6560x; 1.0505x over previous
//
#include <hip/hip_runtime.h>
#include <math.h>

// ---------------------------------------------------------------------------
// SimpleTranslate encoder-decoder forward, MI355X/gfx950.
// Round 4: double-buffered (2-phase) GEMM pipeline with raw s_barrier +
// counted-overlap staging; 64x128 tiles for grid fill; attn loads K/V frags
// at iteration top to overlap L2 latency with softmax.
// ---------------------------------------------------------------------------

typedef __bf16 bf16;
typedef bf16  bf16x8 __attribute__((ext_vector_type(8)));
typedef float f32x4  __attribute__((ext_vector_type(4)));

#define DEV __device__ __forceinline__

DEV f32x4 mfma16(bf16x8 a, bf16x8 b, f32x4 c) {
  return __builtin_amdgcn_mfma_f32_16x16x32_bf16(a, b, c, 0, 0, 0);
}

DEV void async_copy16(const bf16* g, bf16* l) {
  __builtin_amdgcn_global_load_lds(
      (__attribute__((address_space(1))) void*)(g),
      (__attribute__((address_space(3))) void*)(l), 16, 0, 0);
}

// ---------------------------------------------------------------------------
// Fused weight repack: transpose + fp32->bf16 for all weight arrays.
// ---------------------------------------------------------------------------
struct TJob { const float* in; bf16* out; long long oHi, oLo, oOfs; int R, C, zdiv, tile0; };
struct TJobs { TJob j[17]; };

__global__ __launch_bounds__(256) void tcast_all(TJobs JJ, int njobs)
{
  __shared__ float tile[32][33];
  const int t = blockIdx.x;
  int ji = 0;
#pragma unroll
  for (int k = 1; k < 17; ++k) if (k < njobs && JJ.j[k].tile0 <= t) ji = k;
  const TJob J = JJ.j[ji];
  const int rel  = t - J.tile0;
  const int ntx  = J.C >> 5, nty = J.R >> 5;
  const int perz = ntx * nty;
  const int z    = rel / perz;
  const int r2   = rel - z * perz;
  const int bx   = r2 % ntx, by = r2 / ntx;

  const long long zi = (long long)z * J.R * J.C;
  const long long zo = (long long)(z / J.zdiv) * J.oHi + (long long)(z % J.zdiv) * J.oLo + J.oOfs;
  const int c0 = bx * 32, r0 = by * 32;
  const int tx = threadIdx.x & 31, ty = (threadIdx.x >> 5);
#pragma unroll
  for (int i = 0; i < 32; i += 8)
    tile[ty + i][tx] = J.in[zi + (long long)(r0 + ty + i) * J.C + c0 + tx];
  __syncthreads();
#pragma unroll
  for (int i = 0; i < 32; i += 8)
    J.out[zo + (long long)(c0 + ty + i) * J.R + r0 + tx] = (bf16)tile[tx][ty + i];
}

// ---------------------------------------------------------------------------
// Fused embedding + LayerNorm.
// ---------------------------------------------------------------------------
__global__ __launch_bounds__(64) void embedln_kernel(
    const int* __restrict__ tok, const float* __restrict__ temb,
    const float* __restrict__ pemb, float* __restrict__ x,
    const float* __restrict__ w, const float* __restrict__ b,
    bf16* __restrict__ out)
{
  const int row  = blockIdx.x;
  const int sPos = row & 511;
  const int t    = tok[row];
  const int lane = threadIdx.x;
  const int c0   = lane * 8;
  f32x4 a0 = *(const f32x4*)&temb[(long long)t * 512 + c0];
  f32x4 a1 = *(const f32x4*)&temb[(long long)t * 512 + c0 + 4];
  f32x4 p0 = *(const f32x4*)&pemb[(long long)sPos * 512 + c0];
  f32x4 p1 = *(const f32x4*)&pemb[(long long)sPos * 512 + c0 + 4];
  a0 += p0; a1 += p1;
  *(f32x4*)&x[(long long)row * 512 + c0]     = a0;
  *(f32x4*)&x[(long long)row * 512 + c0 + 4] = a1;
  float s = 0.f, q = 0.f;
#pragma unroll
  for (int k = 0; k < 4; ++k) { s += a0[k] + a1[k]; q += a0[k]*a0[k] + a1[k]*a1[k]; }
#pragma unroll
  for (int m = 1; m < 64; m <<= 1) { s += __shfl_xor(s, m); q += __shfl_xor(q, m); }
  const float mean = s * (1.f / 512.f);
  const float var  = q * (1.f / 512.f) - mean * mean;
  const float rs   = rsqrtf(var + 1e-5f);
  f32x4 w0 = *(const f32x4*)&w[c0], w1 = *(const f32x4*)&w[c0 + 4];
  f32x4 b0 = *(const f32x4*)&b[c0], b1 = *(const f32x4*)&b[c0 + 4];
  bf16x8 o;
#pragma unroll
  for (int k = 0; k < 4; ++k) {
    o[k]     = (bf16)((a0[k] - mean) * rs * w0[k] + b0[k]);
    o[k + 4] = (bf16)((a1[k] - mean) * rs * w1[k] + b1[k]);
  }
  *(bf16x8*)&out[(long long)row * 512 + c0] = o;
}

// ---------------------------------------------------------------------------
// Fused residual add + LayerNorm:  x += g + bias;  out = LN(x)*w + bb.
// ---------------------------------------------------------------------------
__global__ __launch_bounds__(256) void addln_kernel(
    const bf16* __restrict__ g, const float* __restrict__ bias,
    float* __restrict__ x, const float* __restrict__ w,
    const float* __restrict__ bb, bf16* __restrict__ out)
{
  const int row  = blockIdx.x * 4 + (threadIdx.x >> 6);
  const int lane = threadIdx.x & 63;
  const int c0   = lane * 8;
  float* xr = x + (long long)row * 512;
  f32x4 a0 = *(const f32x4*)&xr[c0];
  f32x4 a1 = *(const f32x4*)&xr[c0 + 4];
  bf16x8 gv = *(const bf16x8*)&g[(long long)row * 512 + c0];
  f32x4 bi0 = *(const f32x4*)&bias[c0], bi1 = *(const f32x4*)&bias[c0 + 4];
  float v[8];
#pragma unroll
  for (int k = 0; k < 4; ++k) {
    v[k]     = a0[k] + (float)gv[k]     + bi0[k];
    v[k + 4] = a1[k] + (float)gv[k + 4] + bi1[k];
  }
  *(f32x4*)&xr[c0]     = f32x4{v[0], v[1], v[2], v[3]};
  *(f32x4*)&xr[c0 + 4] = f32x4{v[4], v[5], v[6], v[7]};
  float s = 0.f, q = 0.f;
#pragma unroll
  for (int k = 0; k < 8; ++k) { s += v[k]; q += v[k] * v[k]; }
#pragma unroll
  for (int m = 1; m < 64; m <<= 1) { s += __shfl_xor(s, m); q += __shfl_xor(q, m); }
  const float mean = s * (1.f / 512.f);
  const float var  = q * (1.f / 512.f) - mean * mean;
  const float rs   = rsqrtf(var + 1e-5f);
  f32x4 w0 = *(const f32x4*)&w[c0], w1 = *(const f32x4*)&w[c0 + 4];
  f32x4 b0 = *(const f32x4*)&bb[c0], b1 = *(const f32x4*)&bb[c0 + 4];
  bf16x8 o;
#pragma unroll
  for (int k = 0; k < 4; ++k) {
    o[k]     = (bf16)((v[k] - mean) * rs * w0[k] + b0[k]);
    o[k + 4] = (bf16)((v[k + 4] - mean) * rs * w1[k] + b1[k]);
  }
  *(bf16x8*)&out[(long long)row * 512 + c0] = o;
}

// ---------------------------------------------------------------------------
// Flash attention: 1 wave per block, 16 q-rows; K/V direct from L2.
// All 16 K/V fragment loads issue at iteration top (V latency hides under
// softmax). Q pre-scaled by 1/8.
// ---------------------------------------------------------------------------
template <int MODE>
__global__ __launch_bounds__(64) void attn_kernel(
    const bf16* __restrict__ Q, const bf16* __restrict__ K,
    const bf16* __restrict__ Vt, bf16* __restrict__ O,
    const int* __restrict__ srctok)
{
  __shared__ bf16 Pw[16 * 68];
  const int bh = blockIdx.y;
  const int b  = bh >> 3;
  const int q0 = blockIdx.x * 16;
  const int ln = threadIdx.x;
  const int lr = ln & 15, g = ln >> 4;
  const bf16* Qg = Q + ((long long)bh * 512 + q0) * 64;
  const bf16* Kg = K + (long long)bh * 512 * 64;
  const bf16* Vg = Vt + (long long)bh * 64 * 512;
  const int* tkb = srctok + b * 512;

  const bf16x8 aq0 = *(const bf16x8*)&Qg[lr * 64 + g * 8];
  const bf16x8 aq1 = *(const bf16x8*)&Qg[lr * 64 + 32 + g * 8];

  float m[4] = {-1e30f, -1e30f, -1e30f, -1e30f};
  float l[4] = {0.f, 0.f, 0.f, 0.f};
  f32x4 o[4] = {};

  const int ktEnd = (MODE == 1) ? (q0 + 16) : 512;
  for (int kt = 0; kt < ktEnd; kt += 64) {
    // load ALL fragment data for this tile up front
    bf16x8 bk[4][2], bv[4][2];
#pragma unroll
    for (int j = 0; j < 4; ++j) {
      bk[j][0] = *(const bf16x8*)&Kg[(long long)(kt + j * 16 + lr) * 64 + g * 8];
      bk[j][1] = *(const bf16x8*)&Kg[(long long)(kt + j * 16 + lr) * 64 + 32 + g * 8];
    }
#pragma unroll
    for (int n = 0; n < 4; ++n) {
      bv[n][0] = *(const bf16x8*)&Vg[(long long)(n * 16 + lr) * 512 + kt + g * 8];
      bv[n][1] = *(const bf16x8*)&Vg[(long long)(n * 16 + lr) * 512 + kt + 32 + g * 8];
    }
    // S = Q(16) x K_tile(64)^T
    f32x4 sf[4] = {};
#pragma unroll
    for (int j = 0; j < 4; ++j) {
      sf[j] = mfma16(aq0, bk[j][0], sf[j]);
      sf[j] = mfma16(aq1, bk[j][1], sf[j]);
    }
    // mask + row max
    float rm[4] = {-1e30f, -1e30f, -1e30f, -1e30f};
#pragma unroll
    for (int j = 0; j < 4; ++j) {
      if (MODE == 0) {
        const bool ok = (tkb[kt + j * 16 + lr] != 0);
#pragma unroll
        for (int r = 0; r < 4; ++r) if (!ok) sf[j][r] = -1e30f;
      } else {
        const int key = kt + j * 16 + lr;
#pragma unroll
        for (int r = 0; r < 4; ++r)
          if (key > q0 + g * 4 + r) sf[j][r] = -1e30f;
      }
#pragma unroll
      for (int r = 0; r < 4; ++r) rm[r] = fmaxf(rm[r], sf[j][r]);
    }
#pragma unroll
    for (int mk = 1; mk < 16; mk <<= 1)
#pragma unroll
      for (int r = 0; r < 4; ++r) rm[r] = fmaxf(rm[r], __shfl_xor(rm[r], mk));
    float al[4], ps[4] = {0.f, 0.f, 0.f, 0.f};
#pragma unroll
    for (int r = 0; r < 4; ++r) {
      const float mx = fmaxf(m[r], rm[r]);
      al[r] = __expf(m[r] - mx);
      m[r] = mx;
    }
#pragma unroll
    for (int j = 0; j < 4; ++j) {
#pragma unroll
      for (int r = 0; r < 4; ++r) {
        const float p = (sf[j][r] <= -1e29f) ? 0.f : __expf(sf[j][r] - m[r]);
        ps[r] += p;
        Pw[(g * 4 + r) * 68 + j * 16 + lr] = (bf16)p;
      }
    }
#pragma unroll
    for (int mk = 1; mk < 16; mk <<= 1)
#pragma unroll
      for (int r = 0; r < 4; ++r) ps[r] += __shfl_xor(ps[r], mk);
#pragma unroll
    for (int r = 0; r < 4; ++r) l[r] = l[r] * al[r] + ps[r];
#pragma unroll
    for (int n = 0; n < 4; ++n)
#pragma unroll
      for (int r = 0; r < 4; ++r) o[n][r] *= al[r];
    // PV: O(16x64) += P(16x64) x V(64x64)
#pragma unroll
    for (int ks = 0; ks < 2; ++ks) {
      const bf16x8 ap = *(const bf16x8*)&Pw[lr * 68 + ks * 32 + g * 8];
#pragma unroll
      for (int n = 0; n < 4; ++n)
        o[n] = mfma16(ap, bv[n][ks], o[n]);
    }
  }

#pragma unroll
  for (int r = 0; r < 4; ++r) {
    const float inv = 1.f / l[r];
    const long long gr = (long long)b * 512 + q0 + g * 4 + r;
#pragma unroll
    for (int n = 0; n < 4; ++n)
      O[gr * 512 + (bh & 7) * 64 + n * 16 + lr] = (bf16)(o[n][r] * inv);
  }
}

// ---------------------------------------------------------------------------
// bf16 MFMA GEMM, 2-phase double-buffered pipeline (T3-minimum):
//   STAGE(buf0,0); vmcnt(0); barrier;
//   loop: STAGE(buf^1,t+1); compute(buf); waitcnt; barrier; swap.
// Next-tile loads issue BEFORE current compute -> HBM/L2 latency hides.
// Epilogues: 0 bf16; 3 gelu+bias bf16; 4 f32+bias NT (head); 7 qkv scatter;
// 8 per-z cross-KV scatter. SWZ: bijective XCD swizzle (nwg%8==0).
// ---------------------------------------------------------------------------
template <int BM, int BN, int EPI, bool SWZ = false>
__global__ __launch_bounds__(256) void gemm_kernel(
    const bf16* __restrict__ A, const bf16* __restrict__ Bw,
    void* __restrict__ Cc, const float* __restrict__ bias,
    const int K, const int lda, const int ldb, const int ldc,
    const long long sAz, const long long sBz,
    const long long sClo, const long long sChi, const int HB,
    const float scale)
{
  constexpr int BK = 64;
  __shared__ bf16 As[2][BM * BK];
  __shared__ bf16 Bs[2][BN * BK];
  constexpr int AISS = (BM * BK * 2) / 4096;
  constexpr int BISS = (BN * BK * 2) / 4096;

  const int z = blockIdx.z;
  const bf16* Az = A + (long long)z * sAz;
  const bf16* Bz = Bw + (long long)z * sBz;
  const long long cofs = (long long)(z % HB) * sClo + (long long)(z / HB) * sChi;

  const int tid  = threadIdx.x;
  const int wave = tid >> 6;
  const int lane = tid & 63;
  const int lr   = lane & 15;
  const int kg   = lane >> 4;

  int bx = blockIdx.x, by = blockIdx.y;
  if constexpr (SWZ) {
    const int nx = gridDim.x;
    const int nwg = nx * gridDim.y;
    const int id = by * nx + bx;
    const int chunk = nwg >> 3;
    const int swz = (id & 7) * chunk + (id >> 3);
    bx = swz % nx; by = swz / nx;
  }
  const int m0 = bx * BM;
  const int n0 = by * BN;

  constexpr int FM = BM / 32;
  constexpr int FN = BN / 32;
  const int wm = (wave >> 1) * (BM / 2);
  const int wn = (wave & 1) * (BN / 2);

  f32x4 acc[FM][FN] = {};

  auto stage = [&](int buf, int kt) {
#pragma unroll
    for (int i = 0; i < AISS; ++i) {
      const int o = i * 4096 + tid * 16;
      const int r = o >> 7;
      const int c = (o & 127) >> 1;
      async_copy16(Az + (long long)(m0 + r) * lda + kt + c, (bf16*)((char*)&As[buf][0] + o));
    }
#pragma unroll
    for (int i = 0; i < BISS; ++i) {
      const int o = i * 4096 + tid * 16;
      const int r = o >> 7;
      const int c = (o & 127) >> 1;
      async_copy16(Bz + (long long)(n0 + r) * ldb + kt + c, (bf16*)((char*)&Bs[buf][0] + o));
    }
  };

  const int NT = K / BK;
  stage(0, 0);
  asm volatile("s_waitcnt vmcnt(0)" ::: "memory");
  __builtin_amdgcn_s_barrier();
  __builtin_amdgcn_sched_barrier(0);

  int cur = 0;
  for (int t = 0; t < NT; ++t) {
    if (t + 1 < NT) stage(cur ^ 1, (t + 1) * BK);
#pragma unroll
    for (int ks = 0; ks < 2; ++ks) {
      bf16x8 af[FM], bq[FN];
#pragma unroll
      for (int i = 0; i < FM; ++i)
        af[i] = *(const bf16x8*)&As[cur][(wm + i * 16 + lr) * BK + ks * 32 + kg * 8];
#pragma unroll
      for (int j = 0; j < FN; ++j)
        bq[j] = *(const bf16x8*)&Bs[cur][(wn + j * 16 + lr) * BK + ks * 32 + kg * 8];
#pragma unroll
      for (int i = 0; i < FM; ++i)
#pragma unroll
        for (int j = 0; j < FN; ++j)
          acc[i][j] = mfma16(af[i], bq[j], acc[i][j]);
    }
    if (t + 1 < NT) {
      asm volatile("s_waitcnt vmcnt(0) lgkmcnt(0)" ::: "memory");
      __builtin_amdgcn_s_barrier();
      __builtin_amdgcn_sched_barrier(0);
      cur ^= 1;
    }
  }

#pragma unroll
  for (int i = 0; i < FM; ++i) {
#pragma unroll
    for (int j = 0; j < FN; ++j) {
      const int gc = n0 + wn + j * 16 + lr;
#pragma unroll
      for (int r = 0; r < 4; ++r) {
        const int gr = m0 + wm + i * 16 + kg * 4 + r;
        const float v = acc[i][j][r];
        if constexpr (EPI == 0) {
          ((bf16*)Cc + cofs)[(long long)gr * ldc + gc] = (bf16)v;
        } else if constexpr (EPI == 3) {
          float t = v + bias[gc];
          t = 0.5f * t * (1.f + erff(t * 0.70710678118654752f));
          ((bf16*)Cc)[(long long)gr * ldc + gc] = (bf16)t;
        } else if constexpr (EPI == 4) {
          __builtin_nontemporal_store(v + bias[gc], &((float*)Cc)[(long long)gr * ldc + gc]);
        } else if constexpr (EPI == 7) {
          const int sel = gc >> 9;
          const int hh = (gc >> 6) & 7, ee = gc & 63;
          const int bb = gr >> 9, ss = gr & 511;
          bf16* base = (bf16*)Cc + (long long)sel * (2048 * 512);
          const float vv = (sel == 0) ? v * 0.125f : v;
          if (sel < 2) base[(((long long)(bb * 8 + hh) << 9) + ss) * 64 + ee] = (bf16)vv;
          else         base[(((long long)(bb * 8 + hh) << 6) + ee) * 512 + ss] = (bf16)vv;
        } else if constexpr (EPI == 8) {
          const int sel = gc >> 9;
          const int hh = (gc >> 6) & 7, ee = gc & 63;
          const int bb = gr >> 9, ss = gr & 511;
          bf16* base = (bf16*)Cc + (long long)z * sChi + (long long)sel * (2048 * 512);
          if (sel == 0) base[(((long long)(bb * 8 + hh) << 9) + ss) * 64 + ee] = (bf16)v;
          else          base[(((long long)(bb * 8 + hh) << 6) + ee) * 512 + ss] = (bf16)v;
        }
      }
    }
  }
}

// ---------------------------------------------------------------------------
// Host orchestration
// ---------------------------------------------------------------------------
extern "C" void kernel_launch(void* const* d_in, const int* in_sizes, int n_in,
                              void* d_out, int out_size, void* d_ws, size_t ws_size,
                              hipStream_t stream)
{
  const int*   tok_src   = (const int*)d_in[0];
  const int*   tok_dst   = (const int*)d_in[1];
  const float* tok_emb   = (const float*)d_in[2];
  const float* pos_emb   = (const float*)d_in[3];
  const float* enc_ln1_w = (const float*)d_in[4];
  const float* enc_ln1_b = (const float*)d_in[5];
  const float* enc_wq    = (const float*)d_in[6];
  const float* enc_wk    = (const float*)d_in[7];
  const float* enc_wv    = (const float*)d_in[8];
  const float* enc_wo    = (const float*)d_in[9];
  const float* enc_bo    = (const float*)d_in[10];
  const float* enc_ln2_w = (const float*)d_in[11];
  const float* enc_ln2_b = (const float*)d_in[12];
  const float* enc_w1    = (const float*)d_in[13];
  const float* enc_b1    = (const float*)d_in[14];
  const float* enc_w2    = (const float*)d_in[15];
  const float* enc_b2    = (const float*)d_in[16];
  const float* enc_lnf_w = (const float*)d_in[17];
  const float* enc_lnf_b = (const float*)d_in[18];
  const float* dec_ln1_w = (const float*)d_in[19];
  const float* dec_ln1_b = (const float*)d_in[20];
  const float* dec_wq_s  = (const float*)d_in[21];
  const float* dec_wk_s  = (const float*)d_in[22];
  const float* dec_wv_s  = (const float*)d_in[23];
  const float* dec_wo_s  = (const float*)d_in[24];
  const float* dec_bo_s  = (const float*)d_in[25];
  const float* dec_ln2_w = (const float*)d_in[26];
  const float* dec_ln2_b = (const float*)d_in[27];
  const float* dec_wq_c  = (const float*)d_in[28];
  const float* dec_wk_c  = (const float*)d_in[29];
  const float* dec_wv_c  = (const float*)d_in[30];
  const float* dec_wo_c  = (const float*)d_in[31];
  const float* dec_bo_c  = (const float*)d_in[32];
  const float* dec_ln3_w = (const float*)d_in[33];
  const float* dec_ln3_b = (const float*)d_in[34];
  const float* dec_w1    = (const float*)d_in[35];
  const float* dec_b1    = (const float*)d_in[36];
  const float* dec_w2    = (const float*)d_in[37];
  const float* dec_b2    = (const float*)d_in[38];
  const float* dec_lnf_w = (const float*)d_in[39];
  const float* dec_lnf_b = (const float*)d_in[40];
  const float* head_w    = (const float*)d_in[41];
  const float* head_b    = (const float*)d_in[42];
  float* outp = (float*)d_out;

  char* wp = (char*)d_ws;
  auto alloc = [&](size_t nbytes) -> char* {
    char* p = wp; wp += (nbytes + 255) & ~(size_t)255; return p;
  };
  const long long LQKV = 1536LL * 512;
  const long long LKV  = 1024LL * 512;
  const long long LSQ  = 512LL * 512;
  const long long LFF  = 2048LL * 512;
  const long long KVST = 2LL * 2048 * 512;

  bf16* tQKV_e = (bf16*)alloc((size_t)6 * LQKV * 2);
  bf16* tQKV_s = (bf16*)alloc((size_t)6 * LQKV * 2);
  bf16* tQ_c   = (bf16*)alloc((size_t)6 * LSQ * 2);
  bf16* tKV_c  = (bf16*)alloc((size_t)6 * LKV * 2);
  bf16* tWo_e  = (bf16*)alloc((size_t)6 * LSQ * 2);
  bf16* tWo_s  = (bf16*)alloc((size_t)6 * LSQ * 2);
  bf16* tWo_c  = (bf16*)alloc((size_t)6 * LSQ * 2);
  bf16* tW1_e  = (bf16*)alloc((size_t)6 * LFF * 2);
  bf16* tW2_e  = (bf16*)alloc((size_t)6 * LFF * 2);
  bf16* tW1_d  = (bf16*)alloc((size_t)6 * LFF * 2);
  bf16* tW2_d  = (bf16*)alloc((size_t)6 * LFF * 2);
  bf16* tHead  = (bf16*)alloc((size_t)32000 * 512 * 2);

  float* x   = (float*)alloc((size_t)2048 * 512 * 4);
  float* y   = (float*)alloc((size_t)2048 * 512 * 4);
  bf16*  h   = (bf16*)alloc((size_t)2048 * 512 * 2);
  bf16*  qkv = (bf16*)alloc((size_t)3 * 2048 * 512 * 2);
  bf16*  xe  = (bf16*)alloc((size_t)2048 * 512 * 2);
  bf16*  kvc = (bf16*)alloc((size_t)6 * KVST * 2);
  bf16*  ob  = (bf16*)alloc((size_t)2048 * 512 * 2);
  bf16*  t0  = (bf16*)alloc((size_t)2048 * 512 * 2);
  bf16*  h1  = (bf16*)alloc((size_t)2048 * 2048 * 2);
  bf16*  yd  = (bf16*)alloc((size_t)2048 * 512 * 2);

  bf16* ql = qkv;
  bf16* kl = qkv + 2048 * 512;
  bf16* vt = qkv + 2 * 2048 * 512;

  // --- single fused weight repack ---
  TJobs JJ; int nt = 0, nj = 0;
  auto addjob = [&](const float* in, bf16* out, int R, int C,
                    long long oHi, long long oLo, int zdiv, long long oOfs, int nz) {
    JJ.j[nj] = TJob{in, out, oHi, oLo, oOfs, R, C, zdiv, nt};
    nt += (C / 32) * (R / 32) * nz; ++nj;
  };
  addjob(enc_wq,   tQKV_e, 512, 64,   LQKV, 32768, 8, 0,      48);
  addjob(enc_wk,   tQKV_e, 512, 64,   LQKV, 32768, 8, 262144, 48);
  addjob(enc_wv,   tQKV_e, 512, 64,   LQKV, 32768, 8, 524288, 48);
  addjob(dec_wq_s, tQKV_s, 512, 64,   LQKV, 32768, 8, 0,      48);
  addjob(dec_wk_s, tQKV_s, 512, 64,   LQKV, 32768, 8, 262144, 48);
  addjob(dec_wv_s, tQKV_s, 512, 64,   LQKV, 32768, 8, 524288, 48);
  addjob(dec_wq_c, tQ_c,   512, 64,   LSQ,  32768, 8, 0,      48);
  addjob(dec_wk_c, tKV_c,  512, 64,   LKV,  32768, 8, 0,      48);
  addjob(dec_wv_c, tKV_c,  512, 64,   LKV,  32768, 8, 262144, 48);
  addjob(enc_wo,   tWo_e,  512, 512,  LSQ,  0, 1, 0, 6);
  addjob(dec_wo_s, tWo_s,  512, 512,  LSQ,  0, 1, 0, 6);
  addjob(dec_wo_c, tWo_c,  512, 512,  LSQ,  0, 1, 0, 6);
  addjob(enc_w1,   tW1_e,  512, 2048, LFF,  0, 1, 0, 6);
  addjob(enc_w2,   tW2_e,  2048, 512, LFF,  0, 1, 0, 6);
  addjob(dec_w1,   tW1_d,  512, 2048, LFF,  0, 1, 0, 6);
  addjob(dec_w2,   tW2_d,  2048, 512, LFF,  0, 1, 0, 6);
  addjob(head_w,   tHead,  512, 32000, 0,   0, 1, 0, 1);
  tcast_all<<<nt, 256, 0, stream>>>(JJ, nj);

  // ---------------- encoder ----------------
  embedln_kernel<<<2048, 64, 0, stream>>>(tok_src, tok_emb, pos_emb, x, enc_ln1_w, enc_ln1_b, h);
  for (int l = 0; l < 6; ++l) {
    gemm_kernel<64, 128, 7><<<dim3(32, 12, 1), 256, 0, stream>>>(
        h, tQKV_e + (size_t)l * LQKV, qkv, nullptr, 512, 512, 512, 0, 0, 0, 0, 0, 1, 1.f);
    attn_kernel<0><<<dim3(32, 32), 64, 0, stream>>>(ql, kl, vt, ob, tok_src);
    gemm_kernel<64, 64, 0><<<dim3(32, 8, 1), 256, 0, stream>>>(
        ob, tWo_e + (size_t)l * LSQ, t0, nullptr, 512, 512, 512, 512, 0, 0, 0, 0, 1, 1.f);
    addln_kernel<<<512, 256, 0, stream>>>(t0, enc_bo + l * 512, x,
        enc_ln2_w + l * 512, enc_ln2_b + l * 512, h);
    gemm_kernel<64, 128, 3><<<dim3(32, 16, 1), 256, 0, stream>>>(
        h, tW1_e + (size_t)l * LFF, h1, enc_b1 + l * 2048, 512, 512, 512, 2048, 0, 0, 0, 0, 1, 1.f);
    gemm_kernel<64, 64, 0><<<dim3(32, 8, 1), 256, 0, stream>>>(
        h1, tW2_e + (size_t)l * LFF, t0, nullptr, 2048, 2048, 2048, 512, 0, 0, 0, 0, 1, 1.f);
    const float* nw = (l < 5) ? enc_ln1_w + (l + 1) * 512 : enc_lnf_w;
    const float* nb = (l < 5) ? enc_ln1_b + (l + 1) * 512 : enc_lnf_b;
    addln_kernel<<<512, 256, 0, stream>>>(t0, enc_b2 + l * 512, x, nw, nb, (l < 5) ? h : xe);
  }

  // all-layer cross K/V from xe (z = layer)
  gemm_kernel<128, 128, 8><<<dim3(16, 8, 6), 256, 0, stream>>>(
      xe, tKV_c, kvc, nullptr, 512, 512, 512, 0, 0, LKV, 0, KVST, 1, 1.f);

  // ---------------- decoder ----------------
  embedln_kernel<<<2048, 64, 0, stream>>>(tok_dst, tok_emb, pos_emb, y, dec_ln1_w, dec_ln1_b, h);
  for (int l = 0; l < 6; ++l) {
    // self-attention (causal)
    gemm_kernel<64, 128, 7><<<dim3(32, 12, 1), 256, 0, stream>>>(
        h, tQKV_s + (size_t)l * LQKV, qkv, nullptr, 512, 512, 512, 0, 0, 0, 0, 0, 1, 1.f);
    attn_kernel<1><<<dim3(32, 32), 64, 0, stream>>>(ql, kl, vt, ob, nullptr);
    gemm_kernel<64, 64, 0><<<dim3(32, 8, 1), 256, 0, stream>>>(
        ob, tWo_s + (size_t)l * LSQ, t0, nullptr, 512, 512, 512, 512, 0, 0, 0, 0, 1, 1.f);
    addln_kernel<<<512, 256, 0, stream>>>(t0, dec_bo_s + l * 512, y,
        dec_ln2_w + l * 512, dec_ln2_b + l * 512, h);
    // cross-attention (K/V precomputed in kvc)
    gemm_kernel<64, 64, 7><<<dim3(32, 8, 1), 256, 0, stream>>>(
        h, tQ_c + (size_t)l * LSQ, qkv, nullptr, 512, 512, 512, 0, 0, 0, 0, 0, 1, 1.f);
    attn_kernel<0><<<dim3(32, 32), 64, 0, stream>>>(
        ql, kvc + (size_t)l * KVST, kvc + (size_t)l * KVST + 2048 * 512, ob, tok_src);
    gemm_kernel<64, 64, 0><<<dim3(32, 8, 1), 256, 0, stream>>>(
        ob, tWo_c + (size_t)l * LSQ, t0, nullptr, 512, 512, 512, 512, 0, 0, 0, 0, 1, 1.f);
    addln_kernel<<<512, 256, 0, stream>>>(t0, dec_bo_c + l * 512, y,
        dec_ln3_w + l * 512, dec_ln3_b + l * 512, h);
    // FFN
    gemm_kernel<64, 128, 3><<<dim3(32, 16, 1), 256, 0, stream>>>(
        h, tW1_d + (size_t)l * LFF, h1, dec_b1 + l * 2048, 512, 512, 512, 2048, 0, 0, 0, 0, 1, 1.f);
    gemm_kernel<64, 64, 0><<<dim3(32, 8, 1), 256, 0, stream>>>(
        h1, tW2_d + (size_t)l * LFF, t0, nullptr, 2048, 2048, 2048, 512, 0, 0, 0, 0, 1, 1.f);
    const float* nw = (l < 5) ? dec_ln1_w + (l + 1) * 512 : dec_lnf_w;
    const float* nb = (l < 5) ? dec_ln1_b + (l + 1) * 512 : dec_lnf_b;
    addln_kernel<<<512, 256, 0, stream>>>(t0, dec_b2 + l * 512, y, nw, nb, (l < 5) ? h : yd);
  }
  // head: logits [2048, 32000] fp32, XCD-swizzled, nontemporal stores
  gemm_kernel<128, 128, 4, true><<<dim3(16, 250, 1), 256, 0, stream>>>(
      yd, tHead, outp, head_b, 512, 512, 512, 32000, 0, 0, 0, 0, 1, 1.f);
}

// Round 6
// 2032.503 us; speedup vs baseline: 1.7466x; 1.0547x over previous
//
#include <hip/hip_runtime.h>
#include <math.h>

// ---------------------------------------------------------------------------
// SimpleTranslate encoder-decoder forward, MI355X/gfx950.
// Round 5: split-K (WO x2, FFN2 x4) with fp32 partials summed in addln;
// 32-row GEMM tiles for grid fill (2-8 blocks/CU); attn KVBLK=128.
// ---------------------------------------------------------------------------

typedef __bf16 bf16;
typedef bf16  bf16x8 __attribute__((ext_vector_type(8)));
typedef float f32x4  __attribute__((ext_vector_type(4)));

#define DEV __device__ __forceinline__

DEV f32x4 mfma16(bf16x8 a, bf16x8 b, f32x4 c) {
  return __builtin_amdgcn_mfma_f32_16x16x32_bf16(a, b, c, 0, 0, 0);
}

DEV void async_copy16(const bf16* g, bf16* l) {
  __builtin_amdgcn_global_load_lds(
      (__attribute__((address_space(1))) void*)(g),
      (__attribute__((address_space(3))) void*)(l), 16, 0, 0);
}

// ---------------------------------------------------------------------------
// Fused weight repack: transpose + fp32->bf16 for all weight arrays.
// ---------------------------------------------------------------------------
struct TJob { const float* in; bf16* out; long long oHi, oLo, oOfs; int R, C, zdiv, tile0; };
struct TJobs { TJob j[17]; };

__global__ __launch_bounds__(256) void tcast_all(TJobs JJ, int njobs)
{
  __shared__ float tile[32][33];
  const int t = blockIdx.x;
  int ji = 0;
#pragma unroll
  for (int k = 1; k < 17; ++k) if (k < njobs && JJ.j[k].tile0 <= t) ji = k;
  const TJob J = JJ.j[ji];
  const int rel  = t - J.tile0;
  const int ntx  = J.C >> 5, nty = J.R >> 5;
  const int perz = ntx * nty;
  const int z    = rel / perz;
  const int r2   = rel - z * perz;
  const int bx   = r2 % ntx, by = r2 / ntx;

  const long long zi = (long long)z * J.R * J.C;
  const long long zo = (long long)(z / J.zdiv) * J.oHi + (long long)(z % J.zdiv) * J.oLo + J.oOfs;
  const int c0 = bx * 32, r0 = by * 32;
  const int tx = threadIdx.x & 31, ty = (threadIdx.x >> 5);
#pragma unroll
  for (int i = 0; i < 32; i += 8)
    tile[ty + i][tx] = J.in[zi + (long long)(r0 + ty + i) * J.C + c0 + tx];
  __syncthreads();
#pragma unroll
  for (int i = 0; i < 32; i += 8)
    J.out[zo + (long long)(c0 + ty + i) * J.R + r0 + tx] = (bf16)tile[tx][ty + i];
}

// ---------------------------------------------------------------------------
// Fused embedding + LayerNorm, both sequences in one launch (grid 4096).
// ---------------------------------------------------------------------------
__global__ __launch_bounds__(64) void embedln2_kernel(
    const int* __restrict__ tokA, const int* __restrict__ tokB,
    const float* __restrict__ temb, const float* __restrict__ pemb,
    float* __restrict__ xA, float* __restrict__ xB,
    const float* __restrict__ wA, const float* __restrict__ bA,
    const float* __restrict__ wB, const float* __restrict__ bB,
    bf16* __restrict__ outA, bf16* __restrict__ outB)
{
  const bool sB = blockIdx.x >= 2048;
  const int row = sB ? blockIdx.x - 2048 : blockIdx.x;
  const int* tok = sB ? tokB : tokA;
  float* x = sB ? xB : xA;
  const float* w = sB ? wB : wA;
  const float* b = sB ? bB : bA;
  bf16* out = sB ? outB : outA;

  const int sPos = row & 511;
  const int t    = tok[row];
  const int lane = threadIdx.x;
  const int c0   = lane * 8;
  f32x4 a0 = *(const f32x4*)&temb[(long long)t * 512 + c0];
  f32x4 a1 = *(const f32x4*)&temb[(long long)t * 512 + c0 + 4];
  f32x4 p0 = *(const f32x4*)&pemb[(long long)sPos * 512 + c0];
  f32x4 p1 = *(const f32x4*)&pemb[(long long)sPos * 512 + c0 + 4];
  a0 += p0; a1 += p1;
  *(f32x4*)&x[(long long)row * 512 + c0]     = a0;
  *(f32x4*)&x[(long long)row * 512 + c0 + 4] = a1;
  float s = 0.f, q = 0.f;
#pragma unroll
  for (int k = 0; k < 4; ++k) { s += a0[k] + a1[k]; q += a0[k]*a0[k] + a1[k]*a1[k]; }
#pragma unroll
  for (int m = 1; m < 64; m <<= 1) { s += __shfl_xor(s, m); q += __shfl_xor(q, m); }
  const float mean = s * (1.f / 512.f);
  const float var  = q * (1.f / 512.f) - mean * mean;
  const float rs   = rsqrtf(var + 1e-5f);
  f32x4 w0 = *(const f32x4*)&w[c0], w1 = *(const f32x4*)&w[c0 + 4];
  f32x4 b0 = *(const f32x4*)&b[c0], b1 = *(const f32x4*)&b[c0 + 4];
  bf16x8 o;
#pragma unroll
  for (int k = 0; k < 4; ++k) {
    o[k]     = (bf16)((a0[k] - mean) * rs * w0[k] + b0[k]);
    o[k + 4] = (bf16)((a1[k] - mean) * rs * w1[k] + b1[k]);
  }
  *(bf16x8*)&out[(long long)row * 512 + c0] = o;
}

// ---------------------------------------------------------------------------
// Fused split-K reduce + residual add + LayerNorm:
//   x += sum_p part[p] + bias;  out = LN(x)*w + bb.
// part: [P][2048][512] f32. 4 rows per block (one wave per row), grid 512.
// ---------------------------------------------------------------------------
template <int P>
__global__ __launch_bounds__(256) void addln_kernel(
    const float* __restrict__ part, const float* __restrict__ bias,
    float* __restrict__ x, const float* __restrict__ w,
    const float* __restrict__ bb, bf16* __restrict__ out)
{
  const int row  = blockIdx.x * 4 + (threadIdx.x >> 6);
  const int lane = threadIdx.x & 63;
  const int c0   = lane * 8;
  float* xr = x + (long long)row * 512;
  f32x4 a0 = *(const f32x4*)&xr[c0];
  f32x4 a1 = *(const f32x4*)&xr[c0 + 4];
#pragma unroll
  for (int p = 0; p < P; ++p) {
    const float* pr = part + (long long)p * (2048 * 512) + (long long)row * 512;
    a0 += *(const f32x4*)&pr[c0];
    a1 += *(const f32x4*)&pr[c0 + 4];
  }
  f32x4 bi0 = *(const f32x4*)&bias[c0], bi1 = *(const f32x4*)&bias[c0 + 4];
  a0 += bi0; a1 += bi1;
  *(f32x4*)&xr[c0]     = a0;
  *(f32x4*)&xr[c0 + 4] = a1;
  float s = 0.f, q = 0.f;
#pragma unroll
  for (int k = 0; k < 4; ++k) { s += a0[k] + a1[k]; q += a0[k]*a0[k] + a1[k]*a1[k]; }
#pragma unroll
  for (int m = 1; m < 64; m <<= 1) { s += __shfl_xor(s, m); q += __shfl_xor(q, m); }
  const float mean = s * (1.f / 512.f);
  const float var  = q * (1.f / 512.f) - mean * mean;
  const float rs   = rsqrtf(var + 1e-5f);
  f32x4 w0 = *(const f32x4*)&w[c0], w1 = *(const f32x4*)&w[c0 + 4];
  f32x4 b0 = *(const f32x4*)&bb[c0], b1 = *(const f32x4*)&bb[c0 + 4];
  bf16x8 o;
#pragma unroll
  for (int k = 0; k < 4; ++k) {
    o[k]     = (bf16)((a0[k] - mean) * rs * w0[k] + b0[k]);
    o[k + 4] = (bf16)((a1[k] - mean) * rs * w1[k] + b1[k]);
  }
  *(bf16x8*)&out[(long long)row * 512 + c0] = o;
}

// ---------------------------------------------------------------------------
// Flash attention: 1 wave per block, 16 q-rows, KVBLK=128; K/V direct from
// L2. All 32 fragment loads issue at iteration top. Q pre-scaled by 1/8.
// grid (32 q-tiles, 32 bh), block 64.
// ---------------------------------------------------------------------------
template <int MODE>
__global__ __launch_bounds__(64) void attn_kernel(
    const bf16* __restrict__ Q, const bf16* __restrict__ K,
    const bf16* __restrict__ Vt, bf16* __restrict__ O,
    const int* __restrict__ srctok)
{
  __shared__ bf16 Pw[16 * 136];
  const int bh = blockIdx.y;
  const int b  = bh >> 3;
  const int q0 = blockIdx.x * 16;
  const int ln = threadIdx.x;
  const int lr = ln & 15, g = ln >> 4;
  const bf16* Qg = Q + ((long long)bh * 512 + q0) * 64;
  const bf16* Kg = K + (long long)bh * 512 * 64;
  const bf16* Vg = Vt + (long long)bh * 64 * 512;
  const int* tkb = srctok + b * 512;

  const bf16x8 aq0 = *(const bf16x8*)&Qg[lr * 64 + g * 8];
  const bf16x8 aq1 = *(const bf16x8*)&Qg[lr * 64 + 32 + g * 8];

  float m[4] = {-1e30f, -1e30f, -1e30f, -1e30f};
  float l[4] = {0.f, 0.f, 0.f, 0.f};
  f32x4 o[4] = {};

  const int ktEnd = (MODE == 1) ? (q0 + 16) : 512;
  for (int kt = 0; kt < ktEnd; kt += 128) {
    // all loads for this 128-key tile up front (32 x b128, L2-resident)
    bf16x8 bk[8][2], bv[4][4];
#pragma unroll
    for (int j = 0; j < 8; ++j) {
      bk[j][0] = *(const bf16x8*)&Kg[(long long)(kt + j * 16 + lr) * 64 + g * 8];
      bk[j][1] = *(const bf16x8*)&Kg[(long long)(kt + j * 16 + lr) * 64 + 32 + g * 8];
    }
#pragma unroll
    for (int n = 0; n < 4; ++n)
#pragma unroll
      for (int ks = 0; ks < 4; ++ks)
        bv[n][ks] = *(const bf16x8*)&Vg[(long long)(n * 16 + lr) * 512 + kt + ks * 32 + g * 8];

    // S = Q(16) x K_tile(128)^T
    f32x4 sf[8] = {};
#pragma unroll
    for (int j = 0; j < 8; ++j) {
      sf[j] = mfma16(aq0, bk[j][0], sf[j]);
      sf[j] = mfma16(aq1, bk[j][1], sf[j]);
    }
    // mask + row max
    float rm[4] = {-1e30f, -1e30f, -1e30f, -1e30f};
#pragma unroll
    for (int j = 0; j < 8; ++j) {
      if (MODE == 0) {
        const bool ok = (tkb[kt + j * 16 + lr] != 0);
#pragma unroll
        for (int r = 0; r < 4; ++r) if (!ok) sf[j][r] = -1e30f;
      } else {
        const int key = kt + j * 16 + lr;
#pragma unroll
        for (int r = 0; r < 4; ++r)
          if (key > q0 + g * 4 + r) sf[j][r] = -1e30f;
      }
#pragma unroll
      for (int r = 0; r < 4; ++r) rm[r] = fmaxf(rm[r], sf[j][r]);
    }
#pragma unroll
    for (int mk = 1; mk < 16; mk <<= 1)
#pragma unroll
      for (int r = 0; r < 4; ++r) rm[r] = fmaxf(rm[r], __shfl_xor(rm[r], mk));
    float al[4], ps[4] = {0.f, 0.f, 0.f, 0.f};
#pragma unroll
    for (int r = 0; r < 4; ++r) {
      const float mx = fmaxf(m[r], rm[r]);
      al[r] = __expf(m[r] - mx);
      m[r] = mx;
    }
#pragma unroll
    for (int j = 0; j < 8; ++j) {
#pragma unroll
      for (int r = 0; r < 4; ++r) {
        const float p = (sf[j][r] <= -1e29f) ? 0.f : __expf(sf[j][r] - m[r]);
        ps[r] += p;
        Pw[(g * 4 + r) * 136 + j * 16 + lr] = (bf16)p;
      }
    }
#pragma unroll
    for (int mk = 1; mk < 16; mk <<= 1)
#pragma unroll
      for (int r = 0; r < 4; ++r) ps[r] += __shfl_xor(ps[r], mk);
#pragma unroll
    for (int r = 0; r < 4; ++r) l[r] = l[r] * al[r] + ps[r];
#pragma unroll
    for (int n = 0; n < 4; ++n)
#pragma unroll
      for (int r = 0; r < 4; ++r) o[n][r] *= al[r];
    // PV: O(16x64) += P(16x128) x V(128x64)
#pragma unroll
    for (int ks = 0; ks < 4; ++ks) {
      const bf16x8 ap = *(const bf16x8*)&Pw[lr * 136 + ks * 32 + g * 8];
#pragma unroll
      for (int n = 0; n < 4; ++n)
        o[n] = mfma16(ap, bv[n][ks], o[n]);
    }
  }

#pragma unroll
  for (int r = 0; r < 4; ++r) {
    const float inv = 1.f / l[r];
    const long long gr = (long long)b * 512 + q0 + g * 4 + r;
#pragma unroll
    for (int n = 0; n < 4; ++n)
      O[gr * 512 + (bh & 7) * 64 + n * 16 + lr] = (bf16)(o[n][r] * inv);
  }
}

// ---------------------------------------------------------------------------
// bf16 MFMA GEMM, 2-phase double-buffered pipeline.
// Epilogues: 3 gelu+bias bf16; 4 f32+bias NT (head); 7 qkv scatter;
//  8 per-z cross-KV scatter; 9 split-K f32 partial (z = k-chunk, cofs=z*sChi,
//    A/B shifted by z*sAz/z*sBz columns).
// SWZ: bijective XCD swizzle (nwg%8==0).
// ---------------------------------------------------------------------------
template <int BM, int BN, int EPI, bool SWZ = false>
__global__ __launch_bounds__(256) void gemm_kernel(
    const bf16* __restrict__ A, const bf16* __restrict__ Bw,
    void* __restrict__ Cc, const float* __restrict__ bias,
    const int K, const int lda, const int ldb, const int ldc,
    const long long sAz, const long long sBz,
    const long long sClo, const long long sChi, const int HB,
    const float scale)
{
  constexpr int BK = 64;
  __shared__ bf16 As[2][BM * BK];
  __shared__ bf16 Bs[2][BN * BK];
  constexpr int AISS = (BM * BK * 2) / 4096;
  constexpr int BISS = (BN * BK * 2) / 4096;

  const int z = blockIdx.z;
  const bf16* Az = A + (long long)z * sAz;
  const bf16* Bz = Bw + (long long)z * sBz;
  const long long cofs = (long long)(z % HB) * sClo + (long long)(z / HB) * sChi;

  const int tid  = threadIdx.x;
  const int wave = tid >> 6;
  const int lane = tid & 63;
  const int lr   = lane & 15;
  const int kg   = lane >> 4;

  int bx = blockIdx.x, by = blockIdx.y;
  if constexpr (SWZ) {
    const int nx = gridDim.x;
    const int nwg = nx * gridDim.y;
    const int id = by * nx + bx;
    const int chunk = nwg >> 3;
    const int swz = (id & 7) * chunk + (id >> 3);
    bx = swz % nx; by = swz / nx;
  }
  const int m0 = bx * BM;
  const int n0 = by * BN;

  constexpr int FM = BM / 32;
  constexpr int FN = BN / 32;
  const int wm = (wave >> 1) * (BM / 2);
  const int wn = (wave & 1) * (BN / 2);

  f32x4 acc[FM][FN] = {};

  auto stage = [&](int buf, int kt) {
#pragma unroll
    for (int i = 0; i < AISS; ++i) {
      const int o = i * 4096 + tid * 16;
      const int r = o >> 7;
      const int c = (o & 127) >> 1;
      async_copy16(Az + (long long)(m0 + r) * lda + kt + c, (bf16*)((char*)&As[buf][0] + o));
    }
#pragma unroll
    for (int i = 0; i < BISS; ++i) {
      const int o = i * 4096 + tid * 16;
      const int r = o >> 7;
      const int c = (o & 127) >> 1;
      async_copy16(Bz + (long long)(n0 + r) * ldb + kt + c, (bf16*)((char*)&Bs[buf][0] + o));
    }
  };

  const int NT = K / BK;
  stage(0, 0);
  asm volatile("s_waitcnt vmcnt(0)" ::: "memory");
  __builtin_amdgcn_s_barrier();
  __builtin_amdgcn_sched_barrier(0);

  int cur = 0;
  for (int t = 0; t < NT; ++t) {
    if (t + 1 < NT) stage(cur ^ 1, (t + 1) * BK);
#pragma unroll
    for (int ks = 0; ks < 2; ++ks) {
      bf16x8 af[FM], bq[FN];
#pragma unroll
      for (int i = 0; i < FM; ++i)
        af[i] = *(const bf16x8*)&As[cur][(wm + i * 16 + lr) * BK + ks * 32 + kg * 8];
#pragma unroll
      for (int j = 0; j < FN; ++j)
        bq[j] = *(const bf16x8*)&Bs[cur][(wn + j * 16 + lr) * BK + ks * 32 + kg * 8];
#pragma unroll
      for (int i = 0; i < FM; ++i)
#pragma unroll
        for (int j = 0; j < FN; ++j)
          acc[i][j] = mfma16(af[i], bq[j], acc[i][j]);
    }
    if (t + 1 < NT) {
      asm volatile("s_waitcnt vmcnt(0) lgkmcnt(0)" ::: "memory");
      __builtin_amdgcn_s_barrier();
      __builtin_amdgcn_sched_barrier(0);
      cur ^= 1;
    }
  }

#pragma unroll
  for (int i = 0; i < FM; ++i) {
#pragma unroll
    for (int j = 0; j < FN; ++j) {
      const int gc = n0 + wn + j * 16 + lr;
#pragma unroll
      for (int r = 0; r < 4; ++r) {
        const int gr = m0 + wm + i * 16 + kg * 4 + r;
        const float v = acc[i][j][r];
        if constexpr (EPI == 3) {
          float t = v + bias[gc];
          t = 0.5f * t * (1.f + erff(t * 0.70710678118654752f));
          ((bf16*)Cc)[(long long)gr * ldc + gc] = (bf16)t;
        } else if constexpr (EPI == 4) {
          __builtin_nontemporal_store(v + bias[gc], &((float*)Cc)[(long long)gr * ldc + gc]);
        } else if constexpr (EPI == 7) {
          const int sel = gc >> 9;
          const int hh = (gc >> 6) & 7, ee = gc & 63;
          const int bb = gr >> 9, ss = gr & 511;
          bf16* base = (bf16*)Cc + (long long)sel * (2048 * 512);
          const float vv = (sel == 0) ? v * 0.125f : v;
          if (sel < 2) base[(((long long)(bb * 8 + hh) << 9) + ss) * 64 + ee] = (bf16)vv;
          else         base[(((long long)(bb * 8 + hh) << 6) + ee) * 512 + ss] = (bf16)vv;
        } else if constexpr (EPI == 8) {
          const int sel = gc >> 9;
          const int hh = (gc >> 6) & 7, ee = gc & 63;
          const int bb = gr >> 9, ss = gr & 511;
          bf16* base = (bf16*)Cc + (long long)z * sChi + (long long)sel * (2048 * 512);
          if (sel == 0) base[(((long long)(bb * 8 + hh) << 9) + ss) * 64 + ee] = (bf16)v;
          else          base[(((long long)(bb * 8 + hh) << 6) + ee) * 512 + ss] = (bf16)v;
        } else if constexpr (EPI == 9) {
          ((float*)Cc)[cofs + (long long)gr * ldc + gc] = v;
        }
      }
    }
  }
}

// ---------------------------------------------------------------------------
// Host orchestration
// ---------------------------------------------------------------------------
extern "C" void kernel_launch(void* const* d_in, const int* in_sizes, int n_in,
                              void* d_out, int out_size, void* d_ws, size_t ws_size,
                              hipStream_t stream)
{
  const int*   tok_src   = (const int*)d_in[0];
  const int*   tok_dst   = (const int*)d_in[1];
  const float* tok_emb   = (const float*)d_in[2];
  const float* pos_emb   = (const float*)d_in[3];
  const float* enc_ln1_w = (const float*)d_in[4];
  const float* enc_ln1_b = (const float*)d_in[5];
  const float* enc_wq    = (const float*)d_in[6];
  const float* enc_wk    = (const float*)d_in[7];
  const float* enc_wv    = (const float*)d_in[8];
  const float* enc_wo    = (const float*)d_in[9];
  const float* enc_bo    = (const float*)d_in[10];
  const float* enc_ln2_w = (const float*)d_in[11];
  const float* enc_ln2_b = (const float*)d_in[12];
  const float* enc_w1    = (const float*)d_in[13];
  const float* enc_b1    = (const float*)d_in[14];
  const float* enc_w2    = (const float*)d_in[15];
  const float* enc_b2    = (const float*)d_in[16];
  const float* enc_lnf_w = (const float*)d_in[17];
  const float* enc_lnf_b = (const float*)d_in[18];
  const float* dec_ln1_w = (const float*)d_in[19];
  const float* dec_ln1_b = (const float*)d_in[20];
  const float* dec_wq_s  = (const float*)d_in[21];
  const float* dec_wk_s  = (const float*)d_in[22];
  const float* dec_wv_s  = (const float*)d_in[23];
  const float* dec_wo_s  = (const float*)d_in[24];
  const float* dec_bo_s  = (const float*)d_in[25];
  const float* dec_ln2_w = (const float*)d_in[26];
  const float* dec_ln2_b = (const float*)d_in[27];
  const float* dec_wq_c  = (const float*)d_in[28];
  const float* dec_wk_c  = (const float*)d_in[29];
  const float* dec_wv_c  = (const float*)d_in[30];
  const float* dec_wo_c  = (const float*)d_in[31];
  const float* dec_bo_c  = (const float*)d_in[32];
  const float* dec_ln3_w = (const float*)d_in[33];
  const float* dec_ln3_b = (const float*)d_in[34];
  const float* dec_w1    = (const float*)d_in[35];
  const float* dec_b1    = (const float*)d_in[36];
  const float* dec_w2    = (const float*)d_in[37];
  const float* dec_b2    = (const float*)d_in[38];
  const float* dec_lnf_w = (const float*)d_in[39];
  const float* dec_lnf_b = (const float*)d_in[40];
  const float* head_w    = (const float*)d_in[41];
  const float* head_b    = (const float*)d_in[42];
  float* outp = (float*)d_out;

  char* wp = (char*)d_ws;
  auto alloc = [&](size_t nbytes) -> char* {
    char* p = wp; wp += (nbytes + 255) & ~(size_t)255; return p;
  };
  const long long LQKV = 1536LL * 512;
  const long long LKV  = 1024LL * 512;
  const long long LSQ  = 512LL * 512;
  const long long LFF  = 2048LL * 512;
  const long long KVST = 2LL * 2048 * 512;
  const long long PSTR = 2048LL * 512;     // partial stride (f32 elements)

  bf16* tQKV_e = (bf16*)alloc((size_t)6 * LQKV * 2);
  bf16* tQKV_s = (bf16*)alloc((size_t)6 * LQKV * 2);
  bf16* tQ_c   = (bf16*)alloc((size_t)6 * LSQ * 2);
  bf16* tKV_c  = (bf16*)alloc((size_t)6 * LKV * 2);
  bf16* tWo_e  = (bf16*)alloc((size_t)6 * LSQ * 2);
  bf16* tWo_s  = (bf16*)alloc((size_t)6 * LSQ * 2);
  bf16* tWo_c  = (bf16*)alloc((size_t)6 * LSQ * 2);
  bf16* tW1_e  = (bf16*)alloc((size_t)6 * LFF * 2);
  bf16* tW2_e  = (bf16*)alloc((size_t)6 * LFF * 2);
  bf16* tW1_d  = (bf16*)alloc((size_t)6 * LFF * 2);
  bf16* tW2_d  = (bf16*)alloc((size_t)6 * LFF * 2);
  bf16* tHead  = (bf16*)alloc((size_t)32000 * 512 * 2);

  float* x    = (float*)alloc((size_t)2048 * 512 * 4);
  float* y    = (float*)alloc((size_t)2048 * 512 * 4);
  bf16*  h    = (bf16*)alloc((size_t)2048 * 512 * 2);
  bf16*  qkv  = (bf16*)alloc((size_t)3 * 2048 * 512 * 2);
  bf16*  xe   = (bf16*)alloc((size_t)2048 * 512 * 2);
  bf16*  kvc  = (bf16*)alloc((size_t)6 * KVST * 2);
  bf16*  ob   = (bf16*)alloc((size_t)2048 * 512 * 2);
  float* part = (float*)alloc((size_t)4 * PSTR * 4);   // split-K partials
  bf16*  h1   = (bf16*)alloc((size_t)2048 * 2048 * 2);
  bf16*  yd   = (bf16*)alloc((size_t)2048 * 512 * 2);

  bf16* ql = qkv;
  bf16* kl = qkv + 2048 * 512;
  bf16* vt = qkv + 2 * 2048 * 512;

  // --- single fused weight repack ---
  TJobs JJ; int nt = 0, nj = 0;
  auto addjob = [&](const float* in, bf16* out, int R, int C,
                    long long oHi, long long oLo, int zdiv, long long oOfs, int nz) {
    JJ.j[nj] = TJob{in, out, oHi, oLo, oOfs, R, C, zdiv, nt};
    nt += (C / 32) * (R / 32) * nz; ++nj;
  };
  addjob(enc_wq,   tQKV_e, 512, 64,   LQKV, 32768, 8, 0,      48);
  addjob(enc_wk,   tQKV_e, 512, 64,   LQKV, 32768, 8, 262144, 48);
  addjob(enc_wv,   tQKV_e, 512, 64,   LQKV, 32768, 8, 524288, 48);
  addjob(dec_wq_s, tQKV_s, 512, 64,   LQKV, 32768, 8, 0,      48);
  addjob(dec_wk_s, tQKV_s, 512, 64,   LQKV, 32768, 8, 262144, 48);
  addjob(dec_wv_s, tQKV_s, 512, 64,   LQKV, 32768, 8, 524288, 48);
  addjob(dec_wq_c, tQ_c,   512, 64,   LSQ,  32768, 8, 0,      48);
  addjob(dec_wk_c, tKV_c,  512, 64,   LKV,  32768, 8, 0,      48);
  addjob(dec_wv_c, tKV_c,  512, 64,   LKV,  32768, 8, 262144, 48);
  addjob(enc_wo,   tWo_e,  512, 512,  LSQ,  0, 1, 0, 6);
  addjob(dec_wo_s, tWo_s,  512, 512,  LSQ,  0, 1, 0, 6);
  addjob(dec_wo_c, tWo_c,  512, 512,  LSQ,  0, 1, 0, 6);
  addjob(enc_w1,   tW1_e,  512, 2048, LFF,  0, 1, 0, 6);
  addjob(enc_w2,   tW2_e,  2048, 512, LFF,  0, 1, 0, 6);
  addjob(dec_w1,   tW1_d,  512, 2048, LFF,  0, 1, 0, 6);
  addjob(dec_w2,   tW2_d,  2048, 512, LFF,  0, 1, 0, 6);
  addjob(head_w,   tHead,  512, 32000, 0,   0, 1, 0, 1);
  tcast_all<<<nt, 256, 0, stream>>>(JJ, nj);

  // embeddings + first LN for both sequences (one launch)
  embedln2_kernel<<<4096, 64, 0, stream>>>(tok_src, tok_dst, tok_emb, pos_emb,
      x, y, enc_ln1_w, enc_ln1_b, dec_ln1_w, dec_ln1_b, h, yd);
  // (decoder's first h is parked in yd until the decoder loop starts)

  // ---------------- encoder ----------------
  for (int l = 0; l < 6; ++l) {
    gemm_kernel<32, 128, 7><<<dim3(64, 12, 1), 256, 0, stream>>>(
        h, tQKV_e + (size_t)l * LQKV, qkv, nullptr, 512, 512, 512, 0, 0, 0, 0, 0, 1, 1.f);
    attn_kernel<0><<<dim3(32, 32), 64, 0, stream>>>(ql, kl, vt, ob, tok_src);
    gemm_kernel<32, 64, 9><<<dim3(64, 8, 2), 256, 0, stream>>>(
        ob, tWo_e + (size_t)l * LSQ, part, nullptr, 256, 512, 512, 512, 256, 256, 0, PSTR, 1, 1.f);
    addln_kernel<2><<<512, 256, 0, stream>>>(part, enc_bo + l * 512, x,
        enc_ln2_w + l * 512, enc_ln2_b + l * 512, h);
    gemm_kernel<32, 128, 3><<<dim3(64, 16, 1), 256, 0, stream>>>(
        h, tW1_e + (size_t)l * LFF, h1, enc_b1 + l * 2048, 512, 512, 512, 2048, 0, 0, 0, 0, 1, 1.f);
    gemm_kernel<32, 64, 9><<<dim3(64, 8, 4), 256, 0, stream>>>(
        h1, tW2_e + (size_t)l * LFF, part, nullptr, 512, 2048, 2048, 512, 512, 512, 0, PSTR, 1, 1.f);
    const float* nw = (l < 5) ? enc_ln1_w + (l + 1) * 512 : enc_lnf_w;
    const float* nb = (l < 5) ? enc_ln1_b + (l + 1) * 512 : enc_lnf_b;
    addln_kernel<4><<<512, 256, 0, stream>>>(part, enc_b2 + l * 512, x, nw, nb, (l < 5) ? h : xe);
  }

  // all-layer cross K/V from xe (z = layer)
  gemm_kernel<128, 128, 8><<<dim3(16, 8, 6), 256, 0, stream>>>(
      xe, tKV_c, kvc, nullptr, 512, 512, 512, 0, 0, LKV, 0, KVST, 1, 1.f);

  // ---------------- decoder ----------------
  // first decoder h was written to yd by embedln2
  {
    hipMemcpyAsync(h, yd, (size_t)2048 * 512 * 2, hipMemcpyDeviceToDevice, stream);
  }
  for (int l = 0; l < 6; ++l) {
    // self-attention (causal)
    gemm_kernel<32, 128, 7><<<dim3(64, 12, 1), 256, 0, stream>>>(
        h, tQKV_s + (size_t)l * LQKV, qkv, nullptr, 512, 512, 512, 0, 0, 0, 0, 0, 1, 1.f);
    attn_kernel<1><<<dim3(32, 32), 64, 0, stream>>>(ql, kl, vt, ob, nullptr);
    gemm_kernel<32, 64, 9><<<dim3(64, 8, 2), 256, 0, stream>>>(
        ob, tWo_s + (size_t)l * LSQ, part, nullptr, 256, 512, 512, 512, 256, 256, 0, PSTR, 1, 1.f);
    addln_kernel<2><<<512, 256, 0, stream>>>(part, dec_bo_s + l * 512, y,
        dec_ln2_w + l * 512, dec_ln2_b + l * 512, h);
    // cross-attention (K/V precomputed in kvc)
    gemm_kernel<32, 64, 7><<<dim3(64, 8, 1), 256, 0, stream>>>(
        h, tQ_c + (size_t)l * LSQ, qkv, nullptr, 512, 512, 512, 0, 0, 0, 0, 0, 1, 1.f);
    attn_kernel<0><<<dim3(32, 32), 64, 0, stream>>>(
        ql, kvc + (size_t)l * KVST, kvc + (size_t)l * KVST + 2048 * 512, ob, tok_src);
    gemm_kernel<32, 64, 9><<<dim3(64, 8, 2), 256, 0, stream>>>(
        ob, tWo_c + (size_t)l * LSQ, part, nullptr, 256, 512, 512, 512, 256, 256, 0, PSTR, 1, 1.f);
    addln_kernel<2><<<512, 256, 0, stream>>>(part, dec_bo_c + l * 512, y,
        dec_ln3_w + l * 512, dec_ln3_b + l * 512, h);
    // FFN
    gemm_kernel<32, 128, 3><<<dim3(64, 16, 1), 256, 0, stream>>>(
        h, tW1_d + (size_t)l * LFF, h1, dec_b1 + l * 2048, 512, 512, 512, 2048, 0, 0, 0, 0, 1, 1.f);
    gemm_kernel<32, 64, 9><<<dim3(64, 8, 4), 256, 0, stream>>>(
        h1, tW2_d + (size_t)l * LFF, part, nullptr, 512, 2048, 2048, 512, 512, 512, 0, PSTR, 1, 1.f);
    const float* nw = (l < 5) ? dec_ln1_w + (l + 1) * 512 : dec_lnf_w;
    const float* nb = (l < 5) ? dec_ln1_b + (l + 1) * 512 : dec_lnf_b;
    addln_kernel<4><<<512, 256, 0, stream>>>(part, dec_b2 + l * 512, y, nw, nb, (l < 5) ? h : yd);
  }
  // head: logits [2048, 32000] fp32, XCD-swizzled, nontemporal stores
  gemm_kernel<128, 128, 4, true><<<dim3(16, 250, 1), 256, 0, stream>>>(
      yd, tHead, outp, head_b, 512, 512, 512, 32000, 0, 0, 0, 0, 1, 1.f);
}